// Round 11
// baseline (467.528 us; speedup 1.0000x reference)
//
#include <hip/hip_runtime.h>

static constexpr int F = 128;
static constexpr int N_RBF = 20;
static constexpr int N_ATOMS = 8000;
static constexpr int NP = 8064;          // padded to 128 (pad rows hold harness poison = tiny normal floats, benign)
static constexpr int N_EDGES = 160000;
static constexpr int N_MOLS = 100;
static constexpr float CUTOFF = 5.0f;
static constexpr size_t NFC = (size_t)NP * F;   // padded plane-equivalent size (buffer sizing)
static constexpr int REC = 28;           // packed edge record: j, ev, ux,uy,uz, rbf[20], pad[3]
#define PIF 3.14159265358979323846f

typedef __attribute__((ext_vector_type(8))) short bf16x8;
typedef __attribute__((ext_vector_type(4))) float f32x4;
typedef unsigned short ushort_t;
typedef unsigned int uint_t;

__device__ __forceinline__ float silu_f(float x) { return x / (1.f + __expf(-x)); }

__device__ __forceinline__ ushort_t f2bf(float x) {   // round-to-nearest-even
    union { float f; uint_t u; } v; v.f = x;
    uint_t r = v.u + 0x7fffu + ((v.u >> 16) & 1u);
    return (ushort_t)(r >> 16);
}
__device__ __forceinline__ float bf2f(ushort_t h) {
    union { uint_t u; float f; } v; v.u = ((uint_t)h) << 16; return v.f;
}

// split 8 f32 -> hi/lo bf16x8 fragments in registers
__device__ __forceinline__ void split8(const float* e, bf16x8& hi, bf16x8& lo) {
    union { ushort_t u[8]; bf16x8 v; } ph, pl;
    #pragma unroll
    for (int t = 0; t < 8; ++t) {
        ushort_t h = f2bf(e[t]);
        ph.u[t] = h; pl.u[t] = f2bf(e[t] - bf2f(h));
    }
    hi = ph.v; lo = pl.v;
}

// ---------------- edge geometry + live-edge histogram ----------------
__global__ __launch_bounds__(256) void geom_kernel(
    const float* __restrict__ xyz, const int* __restrict__ nbrs,
    float* __restrict__ rbfe, float* __restrict__ envb, float* __restrict__ unitb,
    int* __restrict__ cnt)
{
    int e = blockIdx.x * 256 + threadIdx.x;
    if (e >= N_EDGES) return;
    int i0 = nbrs[2*e+0], i1 = nbrs[2*e+1];
    float dx = xyz[3*i1+0] - xyz[3*i0+0];
    float dy = xyz[3*i1+1] - xyz[3*i0+1];
    float dz = xyz[3*i1+2] - xyz[3*i0+2];
    float d  = sqrtf(dx*dx + dy*dy + dz*dz);
    float inv = 1.f / d;
    unitb[3*e+0] = dx*inv; unitb[3*e+1] = dy*inv; unitb[3*e+2] = dz*inv;
    float ev = (d <= CUTOFF) ? 0.5f*(cosf(PIF*d/CUTOFF) + 1.f) : 0.f;
    envb[e] = ev;
    float base = PIF*d/CUTOFF;
    float sc = inv * ev;   // fold env into rbf (w_s = (rbf*env)@W + b*env)
    #pragma unroll
    for (int k = 0; k < N_RBF; ++k)
        rbfe[e*N_RBF + k] = sinf((float)(k+1)*base) * sc;
    if (ev > 0.f) atomicAdd(&cnt[i0], 1);
}

// ---------------- exclusive scan of 8000 counters (single block) ----------------
__global__ __launch_bounds__(1024) void scan_kernel(
    const int* __restrict__ cnt, int* __restrict__ offsets)
{
    __shared__ int sums[1024];
    int tid = threadIdx.x;
    int base = tid * 8;
    int local[8]; int s = 0;
    #pragma unroll
    for (int i = 0; i < 8; ++i) {
        int idx = base + i;
        local[i] = (idx < N_ATOMS) ? cnt[idx] : 0;
        s += local[i];
    }
    sums[tid] = s;
    __syncthreads();
    for (int d = 1; d < 1024; d <<= 1) {
        int v = (tid >= d) ? sums[tid - d] : 0;
        __syncthreads();
        sums[tid] += v;
        __syncthreads();
    }
    int ex = (tid == 0) ? 0 : sums[tid - 1];
    #pragma unroll
    for (int i = 0; i < 8; ++i) {
        int idx = base + i;
        if (idx < N_ATOMS) { offsets[idx] = ex; ex += local[i]; }
    }
}

// ---------------- scatter: build packed records for live edges (sorted by target) ----------------
__global__ __launch_bounds__(256) void scatter_kernel(
    const int* __restrict__ nbrs, const float* __restrict__ envb,
    const float* __restrict__ rbfe, const float* __restrict__ unitb,
    const int* __restrict__ offsets, int* __restrict__ cursor,
    float* __restrict__ rec)
{
    int e = blockIdx.x * 256 + threadIdx.x;
    if (e >= N_EDGES) return;
    float ev = envb[e];
    if (ev <= 0.f) return;
    int tgt = nbrs[2*e+0];
    int pos = offsets[tgt] + atomicAdd(&cursor[tgt], 1);
    float* r = rec + (size_t)pos * REC;
    r[0] = __int_as_float(nbrs[2*e+1]);
    r[1] = ev;
    r[2] = unitb[3*e+0]; r[3] = unitb[3*e+1]; r[4] = unitb[3*e+2];
    #pragma unroll
    for (int k = 0; k < N_RBF; ++k) r[5 + k] = rbfe[e*N_RBF + k];
}

// ---------------- s = emb_table[z] ----------------
__global__ __launch_bounds__(256) void embed_kernel(
    const float* __restrict__ emb, const int* __restrict__ z, float* __restrict__ s)
{
    int idx = blockIdx.x * 256 + threadIdx.x;   // grid sized exactly N_ATOMS*F
    int n = idx >> 7, f = idx & 127;
    s[idx] = emb[z[n]*F + f];
}

// ---------------- weight prep: transpose + f32 -> (bf16 hi, bf16 lo) ----------------
// dst layout (bf16, [n][k] row-major K-contig), same offsets for hi and lo buffers:
//   W1t  3x(128n x 128k) @ 0        src msg_w1 (128k x 128n)
//   W2t  3x(384n x 128k) @ 49152    src msg_w2
//   UVt  3x(256n x 128k) @ 196608   src upd_u (n 0..127) | upd_v (n 128..255)
//   U1t  3x(128n x 256k) @ 294912   src upd_w1 (256k x 128n)
//   U2t  3x(384n x 128k) @ 393216   src upd_w2
//   ROt  128n x 128k    @ 540672    src ro_w1 (128k x 64n), cols 64..127 zero
//   robias[128] (f32)   idx 557056..557183: ro_b1 padded with zeros
static constexpr int WPREP_W = 557056;
static constexpr int WPREP_TOTAL = 557184;
__global__ __launch_bounds__(256) void wprep_kernel(
    const float* __restrict__ msg_w1, const float* __restrict__ msg_w2,
    const float* __restrict__ upd_u,  const float* __restrict__ upd_v,
    const float* __restrict__ upd_w1, const float* __restrict__ upd_w2,
    const float* __restrict__ ro_w1,  const float* __restrict__ ro_b1,
    ushort_t* __restrict__ dhi, ushort_t* __restrict__ dlo,
    float* __restrict__ robias)
{
    int idx = blockIdx.x * 256 + threadIdx.x;
    if (idx >= WPREP_TOTAL) return;
    if (idx >= WPREP_W) {
        int l = idx - WPREP_W;
        robias[l] = (l < 64) ? ro_b1[l] : 0.f;
        return;
    }
    float val;
    if (idx < 540672) {
        const float* src; int K, N, rem;
        if (idx < 49152)       { int l = idx;          int c = l / 16384; rem = l % 16384; K = 128; N = 128; src = msg_w1 + c * 16384; }
        else if (idx < 196608) { int l = idx - 49152;  int c = l / 49152; rem = l % 49152; K = 128; N = 384; src = msg_w2 + c * 49152; }
        else if (idx < 294912) { int l = idx - 196608; int c = l / 32768; rem = l % 32768; K = 128; N = 128;
                                 if (rem < 16384) src = upd_u + c * 16384;
                                 else { src = upd_v + c * 16384; rem -= 16384; } }
        else if (idx < 393216) { int l = idx - 294912; int c = l / 32768; rem = l % 32768; K = 256; N = 128; src = upd_w1 + c * 32768; }
        else                   { int l = idx - 393216; int c = l / 49152; rem = l % 49152; K = 128; N = 384; src = upd_w2 + c * 49152; }
        int n = rem / K, k = rem % K;
        val = src[k * N + n];
    } else {
        int l = idx - 540672;             // ro_w1 pad: [n][k], n>=64 -> 0
        int n = l >> 7, k = l & 127;
        val = (n < 64) ? ro_w1[k * 64 + n] : 0.f;
    }
    ushort_t h = f2bf(val);
    dhi[idx] = h;
    dlo[idx] = f2bf(val - bf2f(h));
}

// ---------------- direct-load MFMA bf16x3 GEMM (no LDS, no barriers) ----------------
// A f32 MxK (K=128), Bt hi/lo Nc x K bf16 K-contig (L2-resident weights).
// Fragments loaded straight to registers: A = 8 consecutive f32 (32B), B = 8 bf16 (16B).
// TM x 128 tile, 256 threads = 4 waves, each wave 32 N-cols. f32 split-column output.
template<int TM>
__global__ __launch_bounds__(256) void gemm64(
    const float* __restrict__ Af,
    const ushort_t* __restrict__ Bhi, const ushort_t* __restrict__ Blo,
    const float* __restrict__ bias,
    float* __restrict__ C0, float* __restrict__ C1,
    int split, int ld0, int ld1, int act)
{
    constexpr int K = 128;
    constexpr int MI = TM / 16;
    const int tid = threadIdx.x;
    const int wave = tid >> 6, lane = tid & 63;
    const int row_l = lane & 15, quad = lane >> 4;
    const int wn = wave * 32;
    const int m0 = blockIdx.y * TM, n0 = blockIdx.x * 128;

    f32x4 acc[MI][2];
    #pragma unroll
    for (int i = 0; i < MI; ++i)
        #pragma unroll
        for (int j = 0; j < 2; ++j)
            #pragma unroll
            for (int r = 0; r < 4; ++r) acc[i][j][r] = 0.f;

    #pragma unroll
    for (int k0 = 0; k0 < K; k0 += 32) {
        bf16x8 ahf[MI], alf[MI], bhf[2], blf[2];
        #pragma unroll
        for (int i = 0; i < MI; ++i) {
            const float* ap = &Af[(size_t)(m0 + i * 16 + row_l) * K + k0 + quad * 8];
            float e[8];
            float4 v0 = *(const float4*)ap, v1 = *(const float4*)(ap + 4);
            e[0]=v0.x; e[1]=v0.y; e[2]=v0.z; e[3]=v0.w;
            e[4]=v1.x; e[5]=v1.y; e[6]=v1.z; e[7]=v1.w;
            split8(e, ahf[i], alf[i]);
        }
        #pragma unroll
        for (int j = 0; j < 2; ++j) {
            size_t boff = (size_t)(n0 + wn + j * 16 + row_l) * K + k0 + quad * 8;
            bhf[j] = *(const bf16x8*)&Bhi[boff];
            blf[j] = *(const bf16x8*)&Blo[boff];
        }
        #pragma unroll
        for (int i = 0; i < MI; ++i)
            #pragma unroll
            for (int j = 0; j < 2; ++j) {
                acc[i][j] = __builtin_amdgcn_mfma_f32_16x16x32_bf16(ahf[i], bhf[j], acc[i][j], 0, 0, 0);
                acc[i][j] = __builtin_amdgcn_mfma_f32_16x16x32_bf16(ahf[i], blf[j], acc[i][j], 0, 0, 0);
                acc[i][j] = __builtin_amdgcn_mfma_f32_16x16x32_bf16(alf[i], bhf[j], acc[i][j], 0, 0, 0);
            }
    }

    // epilogue: D[row][col]: col = lane&15 (+tiles), row = quad*4 + r (+tiles)
    #pragma unroll
    for (int j = 0; j < 2; ++j) {
        int col = n0 + wn + j * 16 + row_l;
        float bval = bias ? bias[col] : 0.f;
        float* Cp; int ccol, ld;
        if (col < split) { Cp = C0; ccol = col; ld = ld0; }
        else             { Cp = C1; ccol = col - split; ld = ld1; }
        #pragma unroll
        for (int i = 0; i < MI; ++i)
            #pragma unroll
            for (int r = 0; r < 4; ++r) {
                int row = m0 + i * 16 + quad * 4 + r;
                float v = acc[i][j][r] + bval;
                if (act) v = silu_f(v);
                Cp[(size_t)row * ld + ccol] = v;
            }
    }
}

// ---------------- fused MLP (direct-load, 1 barrier): OUT = silu(A@W1+b1)@W2+b2 ----------------
// STACK 0: A = s (K1=128). STACK 1: A = [s | norm(vv)] (K1=256, vv layout [n][3][f]).
// FIN 0: write OUT (Nx384 f32) to C.  FIN 1: keep 'a' in REGISTERS across the 3 column
//        tiles; inline finupd: s += <uv,vv>*a_sv + a_ss ; v += uv*a_vv.
// Only h round-trips LDS (layout change). 32 rows/block, 256 threads = 4 waves.
template<int STACK, int FIN>
__global__ __launch_bounds__(256) void mlp2_kernel(
    const float* __restrict__ sbuf, const float* __restrict__ vvp,
    const ushort_t* __restrict__ W1h, const ushort_t* __restrict__ W1l,
    const float* __restrict__ b1,
    const ushort_t* __restrict__ W2h, const ushort_t* __restrict__ W2l,
    const float* __restrict__ b2,
    float* __restrict__ C,
    const float* __restrict__ uvb, float* __restrict__ v_io, float* __restrict__ s_io)
{
    constexpr int K1 = STACK ? 256 : 128;
    __shared__ __align__(16) ushort_t Hh[32 * 136], Hl[32 * 136];
    const int tid = threadIdx.x;
    const int wave = tid >> 6, lane = tid & 63;
    const int row_l = lane & 15, quad = lane >> 4;
    const int wn = wave * 32;
    const int m0 = blockIdx.x * 32;

    // ---------- stage 1: h = silu(A @ W1 + b1) ----------
    f32x4 acc1[2][2];
    #pragma unroll
    for (int i = 0; i < 2; ++i)
        #pragma unroll
        for (int j = 0; j < 2; ++j)
            #pragma unroll
            for (int r = 0; r < 4; ++r) acc1[i][j][r] = 0.f;

    #pragma unroll 2
    for (int k0 = 0; k0 < K1; k0 += 32) {
        bf16x8 ahf[2], alf[2], bhf[2], blf[2];
        #pragma unroll
        for (int i = 0; i < 2; ++i) {
            int row = m0 + i * 16 + row_l;
            float e[8];
            if (STACK == 0 || k0 < 128) {
                const float* ap = &sbuf[(size_t)row * 128 + k0 + quad * 8];
                float4 v0 = *(const float4*)ap, v1 = *(const float4*)(ap + 4);
                e[0]=v0.x; e[1]=v0.y; e[2]=v0.z; e[3]=v0.w;
                e[4]=v1.x; e[5]=v1.y; e[6]=v1.z; e[7]=v1.w;
            } else {
                int f = k0 - 128 + quad * 8;
                const float* px = &vvp[(size_t)row * 3 * F + f];
                #pragma unroll
                for (int q = 0; q < 2; ++q) {
                    float4 x = *(const float4*)(px + q * 4);
                    float4 y = *(const float4*)(px + F + q * 4);
                    float4 z = *(const float4*)(px + 2 * F + q * 4);
                    e[q*4+0] = sqrtf(x.x*x.x + y.x*y.x + z.x*z.x + 1e-15f);
                    e[q*4+1] = sqrtf(x.y*x.y + y.y*y.y + z.y*z.y + 1e-15f);
                    e[q*4+2] = sqrtf(x.z*x.z + y.z*y.z + z.z*z.z + 1e-15f);
                    e[q*4+3] = sqrtf(x.w*x.w + y.w*y.w + z.w*z.w + 1e-15f);
                }
            }
            split8(e, ahf[i], alf[i]);
        }
        #pragma unroll
        for (int j = 0; j < 2; ++j) {
            size_t boff = (size_t)(wn + j * 16 + row_l) * K1 + k0 + quad * 8;
            bhf[j] = *(const bf16x8*)&W1h[boff];
            blf[j] = *(const bf16x8*)&W1l[boff];
        }
        #pragma unroll
        for (int i = 0; i < 2; ++i)
            #pragma unroll
            for (int j = 0; j < 2; ++j) {
                acc1[i][j] = __builtin_amdgcn_mfma_f32_16x16x32_bf16(ahf[i], bhf[j], acc1[i][j], 0, 0, 0);
                acc1[i][j] = __builtin_amdgcn_mfma_f32_16x16x32_bf16(ahf[i], blf[j], acc1[i][j], 0, 0, 0);
                acc1[i][j] = __builtin_amdgcn_mfma_f32_16x16x32_bf16(alf[i], bhf[j], acc1[i][j], 0, 0, 0);
            }
    }
    // epilogue 1 -> h in LDS (bf16 hi/lo, [row][k] stride 136)
    #pragma unroll
    for (int j = 0; j < 2; ++j) {
        int col = wn + j * 16 + row_l;
        float bval = b1[col];
        #pragma unroll
        for (int i = 0; i < 2; ++i)
            #pragma unroll
            for (int r = 0; r < 4; ++r) {
                int row = i * 16 + quad * 4 + r;
                float v = silu_f(acc1[i][j][r] + bval);
                ushort_t h = f2bf(v);
                Hh[row * 136 + col] = h;
                Hl[row * 136 + col] = f2bf(v - bf2f(h));
            }
    }
    __syncthreads();   // the kernel's ONLY barrier

    // ---------- stage 2: a = h @ W2 + b2, per-ct accumulators stay in registers ----------
    f32x4 acc3[3][2][2];
    #pragma unroll
    for (int ct = 0; ct < 3; ++ct) {
        #pragma unroll
        for (int i = 0; i < 2; ++i)
            #pragma unroll
            for (int j = 0; j < 2; ++j)
                #pragma unroll
                for (int r = 0; r < 4; ++r) acc3[ct][i][j][r] = 0.f;
        #pragma unroll
        for (int k0 = 0; k0 < 128; k0 += 32) {
            bf16x8 ahf[2], alf[2], bhf[2], blf[2];
            #pragma unroll
            for (int i = 0; i < 2; ++i) {
                int ar = (i * 16 + row_l) * 136 + k0 + quad * 8;
                ahf[i] = *(const bf16x8*)&Hh[ar];
                alf[i] = *(const bf16x8*)&Hl[ar];
            }
            #pragma unroll
            for (int j = 0; j < 2; ++j) {
                size_t boff = (size_t)(ct * 128 + wn + j * 16 + row_l) * 128 + k0 + quad * 8;
                bhf[j] = *(const bf16x8*)&W2h[boff];
                blf[j] = *(const bf16x8*)&W2l[boff];
            }
            #pragma unroll
            for (int i = 0; i < 2; ++i)
                #pragma unroll
                for (int j = 0; j < 2; ++j) {
                    acc3[ct][i][j] = __builtin_amdgcn_mfma_f32_16x16x32_bf16(ahf[i], bhf[j], acc3[ct][i][j], 0, 0, 0);
                    acc3[ct][i][j] = __builtin_amdgcn_mfma_f32_16x16x32_bf16(ahf[i], blf[j], acc3[ct][i][j], 0, 0, 0);
                    acc3[ct][i][j] = __builtin_amdgcn_mfma_f32_16x16x32_bf16(alf[i], bhf[j], acc3[ct][i][j], 0, 0, 0);
                }
        }
        if constexpr (FIN == 0) {
            #pragma unroll
            for (int j = 0; j < 2; ++j) {
                int col = ct * 128 + wn + j * 16 + row_l;
                float bval = b2[col];
                #pragma unroll
                for (int i = 0; i < 2; ++i)
                    #pragma unroll
                    for (int r = 0; r < 4; ++r) {
                        int row = i * 16 + quad * 4 + r;
                        C[(size_t)(m0 + row) * 384 + col] = acc3[ct][i][j][r] + bval;
                    }
            }
        }
    }

    // ---------- inline finupd from registers (FIN=1) ----------
    if constexpr (FIN) {
        float b2c[3][2];
        #pragma unroll
        for (int j = 0; j < 2; ++j) {
            int f = wn + j * 16 + row_l;
            b2c[0][j] = b2[f]; b2c[1][j] = b2[128 + f]; b2c[2][j] = b2[256 + f];
        }
        #pragma unroll
        for (int i = 0; i < 2; ++i)
            #pragma unroll
            for (int j = 0; j < 2; ++j)
                #pragma unroll
                for (int r = 0; r < 4; ++r) {
                    int row = i * 16 + quad * 4 + r;
                    int f = wn + j * 16 + row_l;
                    int n = m0 + row;
                    size_t vb = (size_t)n * 3 * F + f;
                    float avv = acc3[0][i][j][r] + b2c[0][j];
                    float asv = acc3[1][i][j][r] + b2c[1][j];
                    float ass = acc3[2][i][j][r] + b2c[2][j];
                    float ux = uvb[vb], uy = uvb[vb + F], uz = uvb[vb + 2*F];
                    float wx = vvp[vb], wy = vvp[vb + F], wz = vvp[vb + 2*F];
                    float dot = ux*wx + uy*wy + uz*wz;
                    s_io[(size_t)n * F + f] += dot * asv + ass;
                    v_io[vb]        += ux * avv;
                    v_io[vb + F]    += uy * avv;
                    v_io[vb + 2*F]  += uz * avv;
                }
    }
}

// ---------------- atom-centric message gather (atomic-free, packed records) ----------------
// v layout: [n][3][f]. ZVIN=1: v_in is implicitly zero (conv 0) — skip reads.
template<int ZVIN>
__global__ __launch_bounds__(128) void msg_gather(
    const float* __restrict__ phi, const float* __restrict__ rec,
    const float* __restrict__ rbf_w, const float* __restrict__ rbf_b,
    const float* __restrict__ v_in, float* __restrict__ s,
    float* __restrict__ v_out, const int* __restrict__ offsets,
    const int* __restrict__ cnt)
{
    const int n = blockIdx.x, tid = threadIdx.x;
    float W0[N_RBF], W1[N_RBF], W2[N_RBF];
    #pragma unroll
    for (int k = 0; k < N_RBF; ++k) {
        W0[k] = rbf_w[k*3*F + tid];
        W1[k] = rbf_w[k*3*F + F + tid];
        W2[k] = rbf_w[k*3*F + 2*F + tid];
    }
    const float b0 = rbf_b[tid], b1 = rbf_b[F + tid], b2 = rbf_b[2*F + tid];
    float ds = 0.f, dvx = 0.f, dvy = 0.f, dvz = 0.f;
    const int off = offsets[n], c = cnt[n];
    const float* r = rec + (size_t)off * REC;
    #pragma unroll 2
    for (int t = 0; t < c; ++t, r += REC) {
        int j = __float_as_int(r[0]);
        float ev = r[1];
        float ux = r[2], uy = r[3], uz = r[4];
        float w0 = b0 * ev, w1 = b1 * ev, w2 = b2 * ev;
        #pragma unroll
        for (int k = 0; k < N_RBF; ++k) {
            float rk = r[5 + k];
            w0 += rk * W0[k]; w1 += rk * W1[k]; w2 += rk * W2[k];
        }
        const float* prow = phi + (size_t)j * 3 * F;
        float s0 = prow[tid] * w0;
        float s1 = prow[F + tid] * w1;
        float s2 = prow[2*F + tid] * w2;
        ds  += s1;
        if constexpr (ZVIN) {
            dvx += s2*ux; dvy += s2*uy; dvz += s2*uz;
        } else {
            const float* vrow = v_in + (size_t)j * 3 * F;
            dvx += s2*ux + s0 * vrow[tid];
            dvy += s2*uy + s0 * vrow[F + tid];
            dvz += s2*uz + s0 * vrow[2*F + tid];
        }
    }
    s[(size_t)n * F + tid] += ds;
    size_t vb = (size_t)n * 3 * F + tid;
    if constexpr (ZVIN) {
        v_out[vb]       = dvx;
        v_out[vb + F]   = dvy;
        v_out[vb + 2*F] = dvz;
    } else {
        v_out[vb]       = v_in[vb]       + dvx;
        v_out[vb + F]   = v_in[vb + F]   + dvy;
        v_out[vb + 2*F] = v_in[vb + 2*F] + dvz;
    }
}

// ---------------- readout reduce: atom_e = h2[n][0:64]·w2 + b2; LDS mol table ----------------
__global__ __launch_bounds__(256) void rreduce_kernel(
    const float* __restrict__ h2, const float* __restrict__ w2,
    const float* __restrict__ b2, const int* __restrict__ mol,
    float* __restrict__ out)
{
    __shared__ float molacc[128];
    int tid = threadIdx.x, wave = tid >> 6, lane = tid & 63;
    if (tid < 128) molacc[tid] = 0.f;
    float w2v = w2[lane], b2v = b2[0];
    int n0 = blockIdx.x * 250;
    __syncthreads();
    for (int t = wave; t < 250; t += 4) {
        int n = n0 + t;
        float val = h2[(size_t)n * 128 + lane] * w2v;
        #pragma unroll
        for (int o = 32; o > 0; o >>= 1) val += __shfl_down(val, o);
        if (lane == 0) atomicAdd(&molacc[mol[n]], val + b2v);
    }
    __syncthreads();
    int lo = mol[n0], hi = mol[n0 + 249];
    for (int m = lo + tid; m <= hi; m += 256)
        atomicAdd(&out[m], molacc[m]);
}

extern "C" void kernel_launch(void* const* d_in, const int* in_sizes, int n_in,
                              void* d_out, int out_size, void* d_ws, size_t ws_size,
                              hipStream_t stream)
{
    const float* xyz    = (const float*)d_in[0];
    const float* emb    = (const float*)d_in[1];
    const float* msg_w1 = (const float*)d_in[2];
    const float* msg_b1 = (const float*)d_in[3];
    const float* msg_w2 = (const float*)d_in[4];
    const float* msg_b2 = (const float*)d_in[5];
    const float* rbf_w  = (const float*)d_in[6];
    const float* rbf_b  = (const float*)d_in[7];
    const float* upd_u  = (const float*)d_in[8];
    const float* upd_v  = (const float*)d_in[9];
    const float* upd_w1 = (const float*)d_in[10];
    const float* upd_b1 = (const float*)d_in[11];
    const float* upd_w2 = (const float*)d_in[12];
    const float* upd_b2 = (const float*)d_in[13];
    const float* ro_w1  = (const float*)d_in[14];
    const float* ro_b1  = (const float*)d_in[15];
    const float* ro_w2  = (const float*)d_in[16];
    const float* ro_b2  = (const float*)d_in[17];
    const int*   z      = (const int*)d_in[18];
    const int*   nbrs   = (const int*)d_in[19];
    const int*   molidx = (const int*)d_in[20];
    float* out = (float*)d_out;

    float* ws = (float*)d_ws;
    size_t off = 0;
    auto alloc = [&](size_t n) { float* p = ws + off; off += n; return p; };
    float* s_buf   = alloc(NFC);
    float* v1_buf  = alloc(3 * NFC);       // [n][3][f]
    float* v2_buf  = alloc(3 * NFC);
    float* uv_buf  = alloc(3 * NFC);
    float* vv_buf  = alloc(3 * NFC);
    float* phi_buf = alloc(3 * NFC);       // phi / readout-hidden
    float* rbfe    = alloc((size_t)N_EDGES * N_RBF);
    float* envb    = alloc(N_EDGES);
    float* unitb   = alloc((size_t)N_EDGES * 3);
    float* edgerec = alloc((size_t)N_EDGES * REC);
    ushort_t* wbf_hi = (ushort_t*)alloc(WPREP_W / 2 + 64);
    ushort_t* wbf_lo = (ushort_t*)alloc(WPREP_W / 2 + 64);
    float* robias   = alloc(128);
    int* cnt        = (int*)alloc(N_ATOMS);
    int* cursor     = (int*)alloc(N_ATOMS);
    int* offsets    = (int*)alloc(N_ATOMS);

    // bf16 weight sub-offsets (elements, see wprep_kernel)
    const size_t oW1 = 0, oW2 = 49152, oUV = 196608, oU1 = 294912, oU2 = 393216, oRO = 540672;

    hipMemsetAsync(out, 0, sizeof(float) * N_MOLS, stream);
    hipMemsetAsync(cnt, 0, sizeof(int) * 2 * N_ATOMS, stream);   // cnt + cursor adjacent

    geom_kernel<<<dim3((N_EDGES + 255) / 256), dim3(256), 0, stream>>>(
        xyz, nbrs, rbfe, envb, unitb, cnt);
    scan_kernel<<<dim3(1), dim3(1024), 0, stream>>>(cnt, offsets);
    scatter_kernel<<<dim3((N_EDGES + 255) / 256), dim3(256), 0, stream>>>(
        nbrs, envb, rbfe, unitb, offsets, cursor, edgerec);
    embed_kernel<<<dim3(N_ATOMS * F / 256), dim3(256), 0, stream>>>(emb, z, s_buf);
    wprep_kernel<<<dim3((WPREP_TOTAL + 255) / 256), dim3(256), 0, stream>>>(
        msg_w1, msg_w2, upd_u, upd_v, upd_w1, upd_w2, ro_w1, ro_b1,
        wbf_hi, wbf_lo, robias);

    float* vin = v1_buf;
    float* vout = v2_buf;
    for (int i = 0; i < 3; ++i) {
        // phi = silu(s@W1+b1)@W2+b2 — fused, direct-load, 1 barrier (252 blocks)
        mlp2_kernel<0, 0><<<dim3(NP/32), dim3(256), 0, stream>>>(
            s_buf, nullptr,
            wbf_hi + oW1 + (size_t)i*16384, wbf_lo + oW1 + (size_t)i*16384,
            msg_b1 + (size_t)i*F,
            wbf_hi + oW2 + (size_t)i*49152, wbf_lo + oW2 + (size_t)i*49152,
            msg_b2 + (size_t)i*3*F,
            phi_buf, nullptr, nullptr, nullptr);
        // atomic-free message gather: s += ds in place; vout = vin + dv
        if (i == 0)
            msg_gather<1><<<dim3(N_ATOMS), dim3(128), 0, stream>>>(
                phi_buf, edgerec, rbf_w + (size_t)i*N_RBF*3*F, rbf_b + (size_t)i*3*F,
                vin, s_buf, vout, offsets, cnt);
        else
            msg_gather<0><<<dim3(N_ATOMS), dim3(128), 0, stream>>>(
                phi_buf, edgerec, rbf_w + (size_t)i*N_RBF*3*F, rbf_b + (size_t)i*3*F,
                vin, s_buf, vout, offsets, cnt);
        // fused u_v|v_v: direct-load GEMM, zero LDS/barriers (756 blocks)
        gemm64<64><<<dim3(2, 3*NP/64), dim3(256), 0, stream>>>(
            vout,
            wbf_hi + oUV + (size_t)i*32768, wbf_lo + oUV + (size_t)i*32768,
            nullptr, uv_buf, vv_buf,
            F, F, F, 0);
        // a = silu([s|norm(vv)]@W1+b1)@W2+b2 + inline register finupd (252 blocks)
        mlp2_kernel<1, 1><<<dim3(NP/32), dim3(256), 0, stream>>>(
            s_buf, vv_buf,
            wbf_hi + oU1 + (size_t)i*32768, wbf_lo + oU1 + (size_t)i*32768,
            upd_b1 + (size_t)i*F,
            wbf_hi + oU2 + (size_t)i*49152, wbf_lo + oU2 + (size_t)i*49152,
            upd_b2 + (size_t)i*3*F,
            nullptr, uv_buf, vout, s_buf);
        float* tmp = vin; vin = vout; vout = tmp;
    }

    // readout: h2 = silu(s @ ro_w1pad + b1pad) via MFMA (252 blocks), then LDS-table reduce
    gemm64<32><<<dim3(1, NP/32), dim3(256), 0, stream>>>(
        s_buf,
        wbf_hi + oRO, wbf_lo + oRO,
        robias, phi_buf, phi_buf,
        128, 128, 128, 1);
    rreduce_kernel<<<dim3(32), dim3(256), 0, stream>>>(
        phi_buf, ro_w2, ro_b2, molidx, out);
}

// Round 12
// 450.027 us; speedup vs baseline: 1.0389x; 1.0389x over previous
//
#include <hip/hip_runtime.h>

static constexpr int F = 128;
static constexpr int N_RBF = 20;
static constexpr int N_ATOMS = 8000;
static constexpr int NP = 8064;          // padded to 128 (pad rows hold harness poison = tiny normal floats, benign)
static constexpr int N_EDGES = 160000;
static constexpr int N_MOLS = 100;
static constexpr float CUTOFF = 5.0f;
static constexpr size_t NFC = (size_t)NP * F;   // padded plane-equivalent size (buffer sizing)
static constexpr int REC = 28;           // packed edge record: j, ev, ux,uy,uz, rbf[20], pad[3]
#define PIF 3.14159265358979323846f

typedef __attribute__((ext_vector_type(8))) short bf16x8;
typedef __attribute__((ext_vector_type(4))) float f32x4;
typedef unsigned short ushort_t;
typedef unsigned int uint_t;

__device__ __forceinline__ float silu_f(float x) { return x / (1.f + __expf(-x)); }

__device__ __forceinline__ ushort_t f2bf(float x) {   // round-to-nearest-even
    union { float f; uint_t u; } v; v.f = x;
    uint_t r = v.u + 0x7fffu + ((v.u >> 16) & 1u);
    return (ushort_t)(r >> 16);
}
__device__ __forceinline__ float bf2f(ushort_t h) {
    union { uint_t u; float f; } v; v.u = ((uint_t)h) << 16; return v.f;
}

// split 8 f32 -> hi/lo bf16x8 fragments in registers
__device__ __forceinline__ void split8(const float* e, bf16x8& hi, bf16x8& lo) {
    union { ushort_t u[8]; bf16x8 v; } ph, pl;
    #pragma unroll
    for (int t = 0; t < 8; ++t) {
        ushort_t h = f2bf(e[t]);
        ph.u[t] = h; pl.u[t] = f2bf(e[t] - bf2f(h));
    }
    hi = ph.v; lo = pl.v;
}

// ---------------- edge geometry + live-edge histogram ----------------
__global__ __launch_bounds__(256) void geom_kernel(
    const float* __restrict__ xyz, const int* __restrict__ nbrs,
    float* __restrict__ rbfe, float* __restrict__ envb, float* __restrict__ unitb,
    int* __restrict__ cnt)
{
    int e = blockIdx.x * 256 + threadIdx.x;
    if (e >= N_EDGES) return;
    int i0 = nbrs[2*e+0], i1 = nbrs[2*e+1];
    float dx = xyz[3*i1+0] - xyz[3*i0+0];
    float dy = xyz[3*i1+1] - xyz[3*i0+1];
    float dz = xyz[3*i1+2] - xyz[3*i0+2];
    float d  = sqrtf(dx*dx + dy*dy + dz*dz);
    float inv = 1.f / d;
    unitb[3*e+0] = dx*inv; unitb[3*e+1] = dy*inv; unitb[3*e+2] = dz*inv;
    float ev = (d <= CUTOFF) ? 0.5f*(cosf(PIF*d/CUTOFF) + 1.f) : 0.f;
    envb[e] = ev;
    float base = PIF*d/CUTOFF;
    float sc = inv * ev;   // fold env into rbf (w_s = (rbf*env)@W + b*env)
    #pragma unroll
    for (int k = 0; k < N_RBF; ++k)
        rbfe[e*N_RBF + k] = sinf((float)(k+1)*base) * sc;
    if (ev > 0.f) atomicAdd(&cnt[i0], 1);
}

// ---------------- exclusive scan of 8000 counters (single block) ----------------
__global__ __launch_bounds__(1024) void scan_kernel(
    const int* __restrict__ cnt, int* __restrict__ offsets)
{
    __shared__ int sums[1024];
    int tid = threadIdx.x;
    int base = tid * 8;
    int local[8]; int s = 0;
    #pragma unroll
    for (int i = 0; i < 8; ++i) {
        int idx = base + i;
        local[i] = (idx < N_ATOMS) ? cnt[idx] : 0;
        s += local[i];
    }
    sums[tid] = s;
    __syncthreads();
    for (int d = 1; d < 1024; d <<= 1) {
        int v = (tid >= d) ? sums[tid - d] : 0;
        __syncthreads();
        sums[tid] += v;
        __syncthreads();
    }
    int ex = (tid == 0) ? 0 : sums[tid - 1];
    #pragma unroll
    for (int i = 0; i < 8; ++i) {
        int idx = base + i;
        if (idx < N_ATOMS) { offsets[idx] = ex; ex += local[i]; }
    }
}

// ---------------- scatter: build packed records for live edges (sorted by target) ----------------
__global__ __launch_bounds__(256) void scatter_kernel(
    const int* __restrict__ nbrs, const float* __restrict__ envb,
    const float* __restrict__ rbfe, const float* __restrict__ unitb,
    const int* __restrict__ offsets, int* __restrict__ cursor,
    float* __restrict__ rec)
{
    int e = blockIdx.x * 256 + threadIdx.x;
    if (e >= N_EDGES) return;
    float ev = envb[e];
    if (ev <= 0.f) return;
    int tgt = nbrs[2*e+0];
    int pos = offsets[tgt] + atomicAdd(&cursor[tgt], 1);
    float* r = rec + (size_t)pos * REC;
    r[0] = __int_as_float(nbrs[2*e+1]);
    r[1] = ev;
    r[2] = unitb[3*e+0]; r[3] = unitb[3*e+1]; r[4] = unitb[3*e+2];
    #pragma unroll
    for (int k = 0; k < N_RBF; ++k) r[5 + k] = rbfe[e*N_RBF + k];
}

// ---------------- s = emb_table[z] ----------------
__global__ __launch_bounds__(256) void embed_kernel(
    const float* __restrict__ emb, const int* __restrict__ z, float* __restrict__ s)
{
    int idx = blockIdx.x * 256 + threadIdx.x;   // grid sized exactly N_ATOMS*F
    int n = idx >> 7, f = idx & 127;
    s[idx] = emb[z[n]*F + f];
}

// ---------------- weight prep: transpose + f32 -> (bf16 hi, bf16 lo) ----------------
// dst layout (bf16, [n][k] row-major K-contig), same offsets for hi and lo buffers:
//   W1t  3x(128n x 128k) @ 0        src msg_w1 (128k x 128n)
//   W2t  3x(384n x 128k) @ 49152    src msg_w2
//   UVt  3x(256n x 128k) @ 196608   src upd_u (n 0..127) | upd_v (n 128..255)
//   U1t  3x(128n x 256k) @ 294912   src upd_w1 (256k x 128n)
//   U2t  3x(384n x 128k) @ 393216   src upd_w2
//   ROt  128n x 128k    @ 540672    src ro_w1 (128k x 64n), cols 64..127 zero
//   robias[128] (f32)   idx 557056..557183: ro_b1 padded with zeros
static constexpr int WPREP_W = 557056;
static constexpr int WPREP_TOTAL = 557184;
__global__ __launch_bounds__(256) void wprep_kernel(
    const float* __restrict__ msg_w1, const float* __restrict__ msg_w2,
    const float* __restrict__ upd_u,  const float* __restrict__ upd_v,
    const float* __restrict__ upd_w1, const float* __restrict__ upd_w2,
    const float* __restrict__ ro_w1,  const float* __restrict__ ro_b1,
    ushort_t* __restrict__ dhi, ushort_t* __restrict__ dlo,
    float* __restrict__ robias)
{
    int idx = blockIdx.x * 256 + threadIdx.x;
    if (idx >= WPREP_TOTAL) return;
    if (idx >= WPREP_W) {
        int l = idx - WPREP_W;
        robias[l] = (l < 64) ? ro_b1[l] : 0.f;
        return;
    }
    float val;
    if (idx < 540672) {
        const float* src; int K, N, rem;
        if (idx < 49152)       { int l = idx;          int c = l / 16384; rem = l % 16384; K = 128; N = 128; src = msg_w1 + c * 16384; }
        else if (idx < 196608) { int l = idx - 49152;  int c = l / 49152; rem = l % 49152; K = 128; N = 384; src = msg_w2 + c * 49152; }
        else if (idx < 294912) { int l = idx - 196608; int c = l / 32768; rem = l % 32768; K = 128; N = 128;
                                 if (rem < 16384) src = upd_u + c * 16384;
                                 else { src = upd_v + c * 16384; rem -= 16384; } }
        else if (idx < 393216) { int l = idx - 294912; int c = l / 32768; rem = l % 32768; K = 256; N = 128; src = upd_w1 + c * 32768; }
        else                   { int l = idx - 393216; int c = l / 49152; rem = l % 49152; K = 128; N = 384; src = upd_w2 + c * 49152; }
        int n = rem / K, k = rem % K;
        val = src[k * N + n];
    } else {
        int l = idx - 540672;             // ro_w1 pad: [n][k], n>=64 -> 0
        int n = l >> 7, k = l & 127;
        val = (n < 64) ? ro_w1[k * 64 + n] : 0.f;
    }
    ushort_t h = f2bf(val);
    dhi[idx] = h;
    dlo[idx] = f2bf(val - bf2f(h));
}

// ---------------- hybrid MFMA bf16x3 GEMM: A staged once in LDS, B direct-load ----------------
// A f32 MxK (K=128), Bt hi/lo Nc x K bf16 K-contig (L2-resident weights).
// One barrier total; k-loop reads A from LDS (ds_read_b128), B straight from global.
// TM x 128 tile, 256 threads = 4 waves, each wave 32 N-cols. f32 split-column output.
template<int TM>
__global__ __launch_bounds__(256) void gemm64(
    const float* __restrict__ Af,
    const ushort_t* __restrict__ Bhi, const ushort_t* __restrict__ Blo,
    const float* __restrict__ bias,
    float* __restrict__ C0, float* __restrict__ C1,
    int split, int ld0, int ld1, int act)
{
    constexpr int K = 128;
    constexpr int MI = TM / 16;
    constexpr int STR = K + 8;             // LDS row stride (bf16 elements)
    __shared__ __align__(16) ushort_t Ah[TM * STR], Al[TM * STR];
    const int tid = threadIdx.x;
    const int wave = tid >> 6, lane = tid & 63;
    const int row_l = lane & 15, quad = lane >> 4;
    const int wn = wave * 32;
    const int m0 = blockIdx.y * TM, n0 = blockIdx.x * 128;

    // ---- stage full A tile once: load f32, split hi/lo, write LDS ----
    {
        constexpr int EA = TM / 2;         // elems/thread (TM*128/256)
        constexpr int TPR = K / EA;        // threads per row
        const int ar = tid / TPR;
        const int ks = (tid % TPR) * EA;
        const float* ap = &Af[(size_t)(m0 + ar) * K + ks];
        #pragma unroll
        for (int q = 0; q < EA / 8; ++q) {
            float e[8];
            float4 v0 = *(const float4*)(ap + q * 8);
            float4 v1 = *(const float4*)(ap + q * 8 + 4);
            e[0]=v0.x; e[1]=v0.y; e[2]=v0.z; e[3]=v0.w;
            e[4]=v1.x; e[5]=v1.y; e[6]=v1.z; e[7]=v1.w;
            bf16x8 hi, lo;
            split8(e, hi, lo);
            *(bf16x8*)&Ah[ar * STR + ks + q * 8] = hi;
            *(bf16x8*)&Al[ar * STR + ks + q * 8] = lo;
        }
    }
    __syncthreads();   // only barrier

    f32x4 acc[MI][2];
    #pragma unroll
    for (int i = 0; i < MI; ++i)
        #pragma unroll
        for (int j = 0; j < 2; ++j)
            #pragma unroll
            for (int r = 0; r < 4; ++r) acc[i][j][r] = 0.f;

    #pragma unroll
    for (int k0 = 0; k0 < K; k0 += 32) {
        bf16x8 ahf[MI], alf[MI], bhf[2], blf[2];
        #pragma unroll
        for (int i = 0; i < MI; ++i) {
            int ar = (i * 16 + row_l) * STR + k0 + quad * 8;
            ahf[i] = *(const bf16x8*)&Ah[ar];
            alf[i] = *(const bf16x8*)&Al[ar];
        }
        #pragma unroll
        for (int j = 0; j < 2; ++j) {
            size_t boff = (size_t)(n0 + wn + j * 16 + row_l) * K + k0 + quad * 8;
            bhf[j] = *(const bf16x8*)&Bhi[boff];
            blf[j] = *(const bf16x8*)&Blo[boff];
        }
        #pragma unroll
        for (int i = 0; i < MI; ++i)
            #pragma unroll
            for (int j = 0; j < 2; ++j) {
                acc[i][j] = __builtin_amdgcn_mfma_f32_16x16x32_bf16(ahf[i], bhf[j], acc[i][j], 0, 0, 0);
                acc[i][j] = __builtin_amdgcn_mfma_f32_16x16x32_bf16(ahf[i], blf[j], acc[i][j], 0, 0, 0);
                acc[i][j] = __builtin_amdgcn_mfma_f32_16x16x32_bf16(alf[i], bhf[j], acc[i][j], 0, 0, 0);
            }
    }

    // epilogue: D[row][col]: col = lane&15 (+tiles), row = quad*4 + r (+tiles)
    #pragma unroll
    for (int j = 0; j < 2; ++j) {
        int col = n0 + wn + j * 16 + row_l;
        float bval = bias ? bias[col] : 0.f;
        float* Cp; int ccol, ld;
        if (col < split) { Cp = C0; ccol = col; ld = ld0; }
        else             { Cp = C1; ccol = col - split; ld = ld1; }
        #pragma unroll
        for (int i = 0; i < MI; ++i)
            #pragma unroll
            for (int r = 0; r < 4; ++r) {
                int row = m0 + i * 16 + quad * 4 + r;
                float v = acc[i][j][r] + bval;
                if (act) v = silu_f(v);
                Cp[(size_t)row * ld + ccol] = v;
            }
    }
}

// ---------------- fused MLP (A staged once, B direct, 2 barriers) ----------------
// OUT = silu(A@W1+b1)@W2+b2.
// STACK 0: A = s (K1=128). STACK 1: A = [s | norm(vv)] (K1=256, vv layout [n][3][f]).
// FIN 0: write OUT (Nx384 f32) to C.  FIN 1: keep 'a' in REGISTERS across the 3 column
//        tiles; inline finupd: s += <uv,vv>*a_sv + a_ss ; v += uv*a_vv.
// 32 rows/block, 256 threads = 4 waves.
template<int STACK, int FIN>
__global__ __launch_bounds__(256) void mlp2_kernel(
    const float* __restrict__ sbuf, const float* __restrict__ vvp,
    const ushort_t* __restrict__ W1h, const ushort_t* __restrict__ W1l,
    const float* __restrict__ b1,
    const ushort_t* __restrict__ W2h, const ushort_t* __restrict__ W2l,
    const float* __restrict__ b2,
    float* __restrict__ C,
    const float* __restrict__ uvb, float* __restrict__ v_io, float* __restrict__ s_io)
{
    constexpr int K1 = STACK ? 256 : 128;
    constexpr int STR1 = K1 + 8;
    __shared__ __align__(16) ushort_t Ah[32 * STR1], Al[32 * STR1];
    __shared__ __align__(16) ushort_t Hh[32 * 136], Hl[32 * 136];
    const int tid = threadIdx.x;
    const int wave = tid >> 6, lane = tid & 63;
    const int row_l = lane & 15, quad = lane >> 4;
    const int wn = wave * 32;
    const int m0 = blockIdx.x * 32;

    // ---- stage full A tile once ----
    {
        constexpr int EA = K1 / 8;          // elems/thread (32*K1/256)
        const int ar = tid >> 3;            // 0..31
        const int ks = (tid & 7) * EA;
        #pragma unroll
        for (int q = 0; q < EA / 8; ++q) {
            int kk = ks + q * 8;
            float e[8];
            if (STACK == 0 || kk < 128) {
                const float* ap = &sbuf[(size_t)(m0 + ar) * 128 + kk];
                float4 v0 = *(const float4*)ap, v1 = *(const float4*)(ap + 4);
                e[0]=v0.x; e[1]=v0.y; e[2]=v0.z; e[3]=v0.w;
                e[4]=v1.x; e[5]=v1.y; e[6]=v1.z; e[7]=v1.w;
            } else {
                int f = kk - 128;
                const float* px = &vvp[(size_t)(m0 + ar) * 3 * F + f];
                #pragma unroll
                for (int qq = 0; qq < 2; ++qq) {
                    float4 x = *(const float4*)(px + qq * 4);
                    float4 y = *(const float4*)(px + F + qq * 4);
                    float4 z = *(const float4*)(px + 2 * F + qq * 4);
                    e[qq*4+0] = sqrtf(x.x*x.x + y.x*y.x + z.x*z.x + 1e-15f);
                    e[qq*4+1] = sqrtf(x.y*x.y + y.y*y.y + z.y*z.y + 1e-15f);
                    e[qq*4+2] = sqrtf(x.z*x.z + y.z*y.z + z.z*z.z + 1e-15f);
                    e[qq*4+3] = sqrtf(x.w*x.w + y.w*y.w + z.w*z.w + 1e-15f);
                }
            }
            bf16x8 hi, lo;
            split8(e, hi, lo);
            *(bf16x8*)&Ah[ar * STR1 + kk] = hi;
            *(bf16x8*)&Al[ar * STR1 + kk] = lo;
        }
    }
    __syncthreads();   // barrier 1

    // ---------- stage 1: h = silu(A @ W1 + b1) ----------
    f32x4 acc1[2][2];
    #pragma unroll
    for (int i = 0; i < 2; ++i)
        #pragma unroll
        for (int j = 0; j < 2; ++j)
            #pragma unroll
            for (int r = 0; r < 4; ++r) acc1[i][j][r] = 0.f;

    #pragma unroll
    for (int k0 = 0; k0 < K1; k0 += 32) {
        bf16x8 ahf[2], alf[2], bhf[2], blf[2];
        #pragma unroll
        for (int i = 0; i < 2; ++i) {
            int ar = (i * 16 + row_l) * STR1 + k0 + quad * 8;
            ahf[i] = *(const bf16x8*)&Ah[ar];
            alf[i] = *(const bf16x8*)&Al[ar];
        }
        #pragma unroll
        for (int j = 0; j < 2; ++j) {
            size_t boff = (size_t)(wn + j * 16 + row_l) * K1 + k0 + quad * 8;
            bhf[j] = *(const bf16x8*)&W1h[boff];
            blf[j] = *(const bf16x8*)&W1l[boff];
        }
        #pragma unroll
        for (int i = 0; i < 2; ++i)
            #pragma unroll
            for (int j = 0; j < 2; ++j) {
                acc1[i][j] = __builtin_amdgcn_mfma_f32_16x16x32_bf16(ahf[i], bhf[j], acc1[i][j], 0, 0, 0);
                acc1[i][j] = __builtin_amdgcn_mfma_f32_16x16x32_bf16(ahf[i], blf[j], acc1[i][j], 0, 0, 0);
                acc1[i][j] = __builtin_amdgcn_mfma_f32_16x16x32_bf16(alf[i], bhf[j], acc1[i][j], 0, 0, 0);
            }
    }
    // epilogue 1 -> h in LDS (bf16 hi/lo, [row][k] stride 136)
    #pragma unroll
    for (int j = 0; j < 2; ++j) {
        int col = wn + j * 16 + row_l;
        float bval = b1[col];
        #pragma unroll
        for (int i = 0; i < 2; ++i)
            #pragma unroll
            for (int r = 0; r < 4; ++r) {
                int row = i * 16 + quad * 4 + r;
                float v = silu_f(acc1[i][j][r] + bval);
                ushort_t h = f2bf(v);
                Hh[row * 136 + col] = h;
                Hl[row * 136 + col] = f2bf(v - bf2f(h));
            }
    }
    __syncthreads();   // barrier 2

    // ---------- stage 2: a = h @ W2 + b2, per-ct accumulators stay in registers ----------
    f32x4 acc3[3][2][2];
    #pragma unroll
    for (int ct = 0; ct < 3; ++ct) {
        #pragma unroll
        for (int i = 0; i < 2; ++i)
            #pragma unroll
            for (int j = 0; j < 2; ++j)
                #pragma unroll
                for (int r = 0; r < 4; ++r) acc3[ct][i][j][r] = 0.f;
        #pragma unroll
        for (int k0 = 0; k0 < 128; k0 += 32) {
            bf16x8 ahf[2], alf[2], bhf[2], blf[2];
            #pragma unroll
            for (int i = 0; i < 2; ++i) {
                int ar = (i * 16 + row_l) * 136 + k0 + quad * 8;
                ahf[i] = *(const bf16x8*)&Hh[ar];
                alf[i] = *(const bf16x8*)&Hl[ar];
            }
            #pragma unroll
            for (int j = 0; j < 2; ++j) {
                size_t boff = (size_t)(ct * 128 + wn + j * 16 + row_l) * 128 + k0 + quad * 8;
                bhf[j] = *(const bf16x8*)&W2h[boff];
                blf[j] = *(const bf16x8*)&W2l[boff];
            }
            #pragma unroll
            for (int i = 0; i < 2; ++i)
                #pragma unroll
                for (int j = 0; j < 2; ++j) {
                    acc3[ct][i][j] = __builtin_amdgcn_mfma_f32_16x16x32_bf16(ahf[i], bhf[j], acc3[ct][i][j], 0, 0, 0);
                    acc3[ct][i][j] = __builtin_amdgcn_mfma_f32_16x16x32_bf16(ahf[i], blf[j], acc3[ct][i][j], 0, 0, 0);
                    acc3[ct][i][j] = __builtin_amdgcn_mfma_f32_16x16x32_bf16(alf[i], bhf[j], acc3[ct][i][j], 0, 0, 0);
                }
        }
        if constexpr (FIN == 0) {
            #pragma unroll
            for (int j = 0; j < 2; ++j) {
                int col = ct * 128 + wn + j * 16 + row_l;
                float bval = b2[col];
                #pragma unroll
                for (int i = 0; i < 2; ++i)
                    #pragma unroll
                    for (int r = 0; r < 4; ++r) {
                        int row = i * 16 + quad * 4 + r;
                        C[(size_t)(m0 + row) * 384 + col] = acc3[ct][i][j][r] + bval;
                    }
            }
        }
    }

    // ---------- inline finupd from registers (FIN=1) ----------
    if constexpr (FIN) {
        float b2c[3][2];
        #pragma unroll
        for (int j = 0; j < 2; ++j) {
            int f = wn + j * 16 + row_l;
            b2c[0][j] = b2[f]; b2c[1][j] = b2[128 + f]; b2c[2][j] = b2[256 + f];
        }
        #pragma unroll
        for (int i = 0; i < 2; ++i)
            #pragma unroll
            for (int j = 0; j < 2; ++j)
                #pragma unroll
                for (int r = 0; r < 4; ++r) {
                    int row = i * 16 + quad * 4 + r;
                    int f = wn + j * 16 + row_l;
                    int n = m0 + row;
                    size_t vb = (size_t)n * 3 * F + f;
                    float avv = acc3[0][i][j][r] + b2c[0][j];
                    float asv = acc3[1][i][j][r] + b2c[1][j];
                    float ass = acc3[2][i][j][r] + b2c[2][j];
                    float ux = uvb[vb], uy = uvb[vb + F], uz = uvb[vb + 2*F];
                    float wx = vvp[vb], wy = vvp[vb + F], wz = vvp[vb + 2*F];
                    float dot = ux*wx + uy*wy + uz*wz;
                    s_io[(size_t)n * F + f] += dot * asv + ass;
                    v_io[vb]        += ux * avv;
                    v_io[vb + F]    += uy * avv;
                    v_io[vb + 2*F]  += uz * avv;
                }
    }
}

// ---------------- atom-centric message gather (atomic-free, packed records) ----------------
// v layout: [n][3][f]. ZVIN=1: v_in is implicitly zero (conv 0) — skip reads.
template<int ZVIN>
__global__ __launch_bounds__(128) void msg_gather(
    const float* __restrict__ phi, const float* __restrict__ rec,
    const float* __restrict__ rbf_w, const float* __restrict__ rbf_b,
    const float* __restrict__ v_in, float* __restrict__ s,
    float* __restrict__ v_out, const int* __restrict__ offsets,
    const int* __restrict__ cnt)
{
    const int n = blockIdx.x, tid = threadIdx.x;
    float W0[N_RBF], W1[N_RBF], W2[N_RBF];
    #pragma unroll
    for (int k = 0; k < N_RBF; ++k) {
        W0[k] = rbf_w[k*3*F + tid];
        W1[k] = rbf_w[k*3*F + F + tid];
        W2[k] = rbf_w[k*3*F + 2*F + tid];
    }
    const float b0 = rbf_b[tid], b1 = rbf_b[F + tid], b2 = rbf_b[2*F + tid];
    float ds = 0.f, dvx = 0.f, dvy = 0.f, dvz = 0.f;
    const int off = offsets[n], c = cnt[n];
    const float* r = rec + (size_t)off * REC;
    #pragma unroll 2
    for (int t = 0; t < c; ++t, r += REC) {
        int j = __float_as_int(r[0]);
        float ev = r[1];
        float ux = r[2], uy = r[3], uz = r[4];
        float w0 = b0 * ev, w1 = b1 * ev, w2 = b2 * ev;
        #pragma unroll
        for (int k = 0; k < N_RBF; ++k) {
            float rk = r[5 + k];
            w0 += rk * W0[k]; w1 += rk * W1[k]; w2 += rk * W2[k];
        }
        const float* prow = phi + (size_t)j * 3 * F;
        float s0 = prow[tid] * w0;
        float s1 = prow[F + tid] * w1;
        float s2 = prow[2*F + tid] * w2;
        ds  += s1;
        if constexpr (ZVIN) {
            dvx += s2*ux; dvy += s2*uy; dvz += s2*uz;
        } else {
            const float* vrow = v_in + (size_t)j * 3 * F;
            dvx += s2*ux + s0 * vrow[tid];
            dvy += s2*uy + s0 * vrow[F + tid];
            dvz += s2*uz + s0 * vrow[2*F + tid];
        }
    }
    s[(size_t)n * F + tid] += ds;
    size_t vb = (size_t)n * 3 * F + tid;
    if constexpr (ZVIN) {
        v_out[vb]       = dvx;
        v_out[vb + F]   = dvy;
        v_out[vb + 2*F] = dvz;
    } else {
        v_out[vb]       = v_in[vb]       + dvx;
        v_out[vb + F]   = v_in[vb + F]   + dvy;
        v_out[vb + 2*F] = v_in[vb + 2*F] + dvz;
    }
}

// ---------------- readout reduce: atom_e = h2[n][0:64]·w2 + b2; LDS mol table ----------------
__global__ __launch_bounds__(256) void rreduce_kernel(
    const float* __restrict__ h2, const float* __restrict__ w2,
    const float* __restrict__ b2, const int* __restrict__ mol,
    float* __restrict__ out)
{
    __shared__ float molacc[128];
    int tid = threadIdx.x, wave = tid >> 6, lane = tid & 63;
    if (tid < 128) molacc[tid] = 0.f;
    float w2v = w2[lane], b2v = b2[0];
    int n0 = blockIdx.x * 250;
    __syncthreads();
    for (int t = wave; t < 250; t += 4) {
        int n = n0 + t;
        float val = h2[(size_t)n * 128 + lane] * w2v;
        #pragma unroll
        for (int o = 32; o > 0; o >>= 1) val += __shfl_down(val, o);
        if (lane == 0) atomicAdd(&molacc[mol[n]], val + b2v);
    }
    __syncthreads();
    int lo = mol[n0], hi = mol[n0 + 249];
    for (int m = lo + tid; m <= hi; m += 256)
        atomicAdd(&out[m], molacc[m]);
}

extern "C" void kernel_launch(void* const* d_in, const int* in_sizes, int n_in,
                              void* d_out, int out_size, void* d_ws, size_t ws_size,
                              hipStream_t stream)
{
    const float* xyz    = (const float*)d_in[0];
    const float* emb    = (const float*)d_in[1];
    const float* msg_w1 = (const float*)d_in[2];
    const float* msg_b1 = (const float*)d_in[3];
    const float* msg_w2 = (const float*)d_in[4];
    const float* msg_b2 = (const float*)d_in[5];
    const float* rbf_w  = (const float*)d_in[6];
    const float* rbf_b  = (const float*)d_in[7];
    const float* upd_u  = (const float*)d_in[8];
    const float* upd_v  = (const float*)d_in[9];
    const float* upd_w1 = (const float*)d_in[10];
    const float* upd_b1 = (const float*)d_in[11];
    const float* upd_w2 = (const float*)d_in[12];
    const float* upd_b2 = (const float*)d_in[13];
    const float* ro_w1  = (const float*)d_in[14];
    const float* ro_b1  = (const float*)d_in[15];
    const float* ro_w2  = (const float*)d_in[16];
    const float* ro_b2  = (const float*)d_in[17];
    const int*   z      = (const int*)d_in[18];
    const int*   nbrs   = (const int*)d_in[19];
    const int*   molidx = (const int*)d_in[20];
    float* out = (float*)d_out;

    float* ws = (float*)d_ws;
    size_t off = 0;
    auto alloc = [&](size_t n) { float* p = ws + off; off += n; return p; };
    float* s_buf   = alloc(NFC);
    float* v1_buf  = alloc(3 * NFC);       // [n][3][f]
    float* v2_buf  = alloc(3 * NFC);
    float* uv_buf  = alloc(3 * NFC);
    float* vv_buf  = alloc(3 * NFC);
    float* phi_buf = alloc(3 * NFC);       // phi / readout-hidden
    float* rbfe    = alloc((size_t)N_EDGES * N_RBF);
    float* envb    = alloc(N_EDGES);
    float* unitb   = alloc((size_t)N_EDGES * 3);
    float* edgerec = alloc((size_t)N_EDGES * REC);
    ushort_t* wbf_hi = (ushort_t*)alloc(WPREP_W / 2 + 64);
    ushort_t* wbf_lo = (ushort_t*)alloc(WPREP_W / 2 + 64);
    float* robias   = alloc(128);
    int* cnt        = (int*)alloc(N_ATOMS);
    int* cursor     = (int*)alloc(N_ATOMS);
    int* offsets    = (int*)alloc(N_ATOMS);

    // bf16 weight sub-offsets (elements, see wprep_kernel)
    const size_t oW1 = 0, oW2 = 49152, oUV = 196608, oU1 = 294912, oU2 = 393216, oRO = 540672;

    hipMemsetAsync(out, 0, sizeof(float) * N_MOLS, stream);
    hipMemsetAsync(cnt, 0, sizeof(int) * 2 * N_ATOMS, stream);   // cnt + cursor adjacent

    geom_kernel<<<dim3((N_EDGES + 255) / 256), dim3(256), 0, stream>>>(
        xyz, nbrs, rbfe, envb, unitb, cnt);
    scan_kernel<<<dim3(1), dim3(1024), 0, stream>>>(cnt, offsets);
    scatter_kernel<<<dim3((N_EDGES + 255) / 256), dim3(256), 0, stream>>>(
        nbrs, envb, rbfe, unitb, offsets, cursor, edgerec);
    embed_kernel<<<dim3(N_ATOMS * F / 256), dim3(256), 0, stream>>>(emb, z, s_buf);
    wprep_kernel<<<dim3((WPREP_TOTAL + 255) / 256), dim3(256), 0, stream>>>(
        msg_w1, msg_w2, upd_u, upd_v, upd_w1, upd_w2, ro_w1, ro_b1,
        wbf_hi, wbf_lo, robias);

    float* vin = v1_buf;
    float* vout = v2_buf;
    for (int i = 0; i < 3; ++i) {
        // phi = silu(s@W1+b1)@W2+b2 — fused, A staged once, B direct (252 blocks)
        mlp2_kernel<0, 0><<<dim3(NP/32), dim3(256), 0, stream>>>(
            s_buf, nullptr,
            wbf_hi + oW1 + (size_t)i*16384, wbf_lo + oW1 + (size_t)i*16384,
            msg_b1 + (size_t)i*F,
            wbf_hi + oW2 + (size_t)i*49152, wbf_lo + oW2 + (size_t)i*49152,
            msg_b2 + (size_t)i*3*F,
            phi_buf, nullptr, nullptr, nullptr);
        // atomic-free message gather: s += ds in place; vout = vin + dv
        if (i == 0)
            msg_gather<1><<<dim3(N_ATOMS), dim3(128), 0, stream>>>(
                phi_buf, edgerec, rbf_w + (size_t)i*N_RBF*3*F, rbf_b + (size_t)i*3*F,
                vin, s_buf, vout, offsets, cnt);
        else
            msg_gather<0><<<dim3(N_ATOMS), dim3(128), 0, stream>>>(
                phi_buf, edgerec, rbf_w + (size_t)i*N_RBF*3*F, rbf_b + (size_t)i*3*F,
                vin, s_buf, vout, offsets, cnt);
        // fused u_v|v_v: hybrid GEMM, 1 barrier (756 blocks)
        gemm64<64><<<dim3(2, 3*NP/64), dim3(256), 0, stream>>>(
            vout,
            wbf_hi + oUV + (size_t)i*32768, wbf_lo + oUV + (size_t)i*32768,
            nullptr, uv_buf, vv_buf,
            F, F, F, 0);
        // a = silu([s|norm(vv)]@W1+b1)@W2+b2 + inline register finupd (252 blocks)
        mlp2_kernel<1, 1><<<dim3(NP/32), dim3(256), 0, stream>>>(
            s_buf, vv_buf,
            wbf_hi + oU1 + (size_t)i*32768, wbf_lo + oU1 + (size_t)i*32768,
            upd_b1 + (size_t)i*F,
            wbf_hi + oU2 + (size_t)i*49152, wbf_lo + oU2 + (size_t)i*49152,
            upd_b2 + (size_t)i*3*F,
            nullptr, uv_buf, vout, s_buf);
        float* tmp = vin; vin = vout; vout = tmp;
    }

    // readout: h2 = silu(s @ ro_w1pad + b1pad) via MFMA (252 blocks), then LDS-table reduce
    gemm64<32><<<dim3(1, NP/32), dim3(256), 0, stream>>>(
        s_buf,
        wbf_hi + oRO, wbf_lo + oRO,
        robias, phi_buf, phi_buf,
        128, 128, 128, 1);
    rreduce_kernel<<<dim3(32), dim3(256), 0, stream>>>(
        phi_buf, ro_w2, ro_b2, molidx, out);
}

// Round 13
// 424.008 us; speedup vs baseline: 1.1026x; 1.0614x over previous
//
#include <hip/hip_runtime.h>

static constexpr int F = 128;
static constexpr int N_RBF = 20;
static constexpr int N_ATOMS = 8000;
static constexpr int NP = 8064;          // padded to 128 (pad rows hold harness poison = tiny normal floats, benign)
static constexpr int N_EDGES = 160000;
static constexpr int N_MOLS = 100;
static constexpr float CUTOFF = 5.0f;
static constexpr size_t NFC = (size_t)NP * F;   // padded plane-equivalent size (buffer sizing)
static constexpr int REC = 28;           // packed edge record: j, ev, ux,uy,uz, rbf[20], pad[3]
#define PIF 3.14159265358979323846f

typedef __attribute__((ext_vector_type(8))) short bf16x8;
typedef __attribute__((ext_vector_type(4))) float f32x4;
typedef unsigned short ushort_t;
typedef unsigned int uint_t;

__device__ __forceinline__ float silu_f(float x) { return x / (1.f + __expf(-x)); }

__device__ __forceinline__ ushort_t f2bf(float x) {   // round-to-nearest-even
    union { float f; uint_t u; } v; v.f = x;
    uint_t r = v.u + 0x7fffu + ((v.u >> 16) & 1u);
    return (ushort_t)(r >> 16);
}
__device__ __forceinline__ float bf2f(ushort_t h) {
    union { uint_t u; float f; } v; v.u = ((uint_t)h) << 16; return v.f;
}

// ---------------- edge geometry + live-edge histogram ----------------
__global__ __launch_bounds__(256) void geom_kernel(
    const float* __restrict__ xyz, const int* __restrict__ nbrs,
    float* __restrict__ rbfe, float* __restrict__ envb, float* __restrict__ unitb,
    int* __restrict__ cnt)
{
    int e = blockIdx.x * 256 + threadIdx.x;
    if (e >= N_EDGES) return;
    int i0 = nbrs[2*e+0], i1 = nbrs[2*e+1];
    float dx = xyz[3*i1+0] - xyz[3*i0+0];
    float dy = xyz[3*i1+1] - xyz[3*i0+1];
    float dz = xyz[3*i1+2] - xyz[3*i0+2];
    float d  = sqrtf(dx*dx + dy*dy + dz*dz);
    float inv = 1.f / d;
    unitb[3*e+0] = dx*inv; unitb[3*e+1] = dy*inv; unitb[3*e+2] = dz*inv;
    float ev = (d <= CUTOFF) ? 0.5f*(cosf(PIF*d/CUTOFF) + 1.f) : 0.f;
    envb[e] = ev;
    float base = PIF*d/CUTOFF;
    float sc = inv * ev;   // fold env into rbf (w_s = (rbf*env)@W + b*env)
    #pragma unroll
    for (int k = 0; k < N_RBF; ++k)
        rbfe[e*N_RBF + k] = sinf((float)(k+1)*base) * sc;
    if (ev > 0.f) atomicAdd(&cnt[i0], 1);
}

// ---------------- exclusive scan of 8000 counters (single block) ----------------
__global__ __launch_bounds__(1024) void scan_kernel(
    const int* __restrict__ cnt, int* __restrict__ offsets)
{
    __shared__ int sums[1024];
    int tid = threadIdx.x;
    int base = tid * 8;
    int local[8]; int s = 0;
    #pragma unroll
    for (int i = 0; i < 8; ++i) {
        int idx = base + i;
        local[i] = (idx < N_ATOMS) ? cnt[idx] : 0;
        s += local[i];
    }
    sums[tid] = s;
    __syncthreads();
    for (int d = 1; d < 1024; d <<= 1) {
        int v = (tid >= d) ? sums[tid - d] : 0;
        __syncthreads();
        sums[tid] += v;
        __syncthreads();
    }
    int ex = (tid == 0) ? 0 : sums[tid - 1];
    #pragma unroll
    for (int i = 0; i < 8; ++i) {
        int idx = base + i;
        if (idx < N_ATOMS) { offsets[idx] = ex; ex += local[i]; }
    }
}

// ---------------- scatter: build packed records for live edges (sorted by target) ----------------
__global__ __launch_bounds__(256) void scatter_kernel(
    const int* __restrict__ nbrs, const float* __restrict__ envb,
    const float* __restrict__ rbfe, const float* __restrict__ unitb,
    const int* __restrict__ offsets, int* __restrict__ cursor,
    float* __restrict__ rec)
{
    int e = blockIdx.x * 256 + threadIdx.x;
    if (e >= N_EDGES) return;
    float ev = envb[e];
    if (ev <= 0.f) return;
    int tgt = nbrs[2*e+0];
    int pos = offsets[tgt] + atomicAdd(&cursor[tgt], 1);
    float* r = rec + (size_t)pos * REC;
    r[0] = __int_as_float(nbrs[2*e+1]);
    r[1] = ev;
    r[2] = unitb[3*e+0]; r[3] = unitb[3*e+1]; r[4] = unitb[3*e+2];
    #pragma unroll
    for (int k = 0; k < N_RBF; ++k) r[5 + k] = rbfe[e*N_RBF + k];
}

// ---------------- s = emb_table[z] ----------------
__global__ __launch_bounds__(256) void embed_kernel(
    const float* __restrict__ emb, const int* __restrict__ z, float* __restrict__ s)
{
    int idx = blockIdx.x * 256 + threadIdx.x;   // grid sized exactly N_ATOMS*F
    int n = idx >> 7, f = idx & 127;
    s[idx] = emb[z[n]*F + f];
}

// ---------------- weight prep: transpose + f32 -> (bf16 hi, bf16 lo) ----------------
// dst layout (bf16, [n][k] row-major K-contig), same offsets for hi and lo buffers:
//   W1t  3x(128n x 128k) @ 0        src msg_w1 (128k x 128n)
//   W2t  3x(384n x 128k) @ 49152    src msg_w2
//   UVt  3x(256n x 128k) @ 196608   src upd_u (n 0..127) | upd_v (n 128..255)
//   U1t  3x(128n x 256k) @ 294912   src upd_w1 (256k x 128n)
//   U2t  3x(384n x 128k) @ 393216   src upd_w2
//   ROt  128n x 128k    @ 540672    src ro_w1 (128k x 64n), cols 64..127 zero
//   robias[128] (f32)   idx 557056..557183: ro_b1 padded with zeros
static constexpr int WPREP_W = 557056;
static constexpr int WPREP_TOTAL = 557184;
__global__ __launch_bounds__(256) void wprep_kernel(
    const float* __restrict__ msg_w1, const float* __restrict__ msg_w2,
    const float* __restrict__ upd_u,  const float* __restrict__ upd_v,
    const float* __restrict__ upd_w1, const float* __restrict__ upd_w2,
    const float* __restrict__ ro_w1,  const float* __restrict__ ro_b1,
    ushort_t* __restrict__ dhi, ushort_t* __restrict__ dlo,
    float* __restrict__ robias)
{
    int idx = blockIdx.x * 256 + threadIdx.x;
    if (idx >= WPREP_TOTAL) return;
    if (idx >= WPREP_W) {
        int l = idx - WPREP_W;
        robias[l] = (l < 64) ? ro_b1[l] : 0.f;
        return;
    }
    float val;
    if (idx < 540672) {
        const float* src; int K, N, rem;
        if (idx < 49152)       { int l = idx;          int c = l / 16384; rem = l % 16384; K = 128; N = 128; src = msg_w1 + c * 16384; }
        else if (idx < 196608) { int l = idx - 49152;  int c = l / 49152; rem = l % 49152; K = 128; N = 384; src = msg_w2 + c * 49152; }
        else if (idx < 294912) { int l = idx - 196608; int c = l / 32768; rem = l % 32768; K = 128; N = 128;
                                 if (rem < 16384) src = upd_u + c * 16384;
                                 else { src = upd_v + c * 16384; rem -= 16384; } }
        else if (idx < 393216) { int l = idx - 294912; int c = l / 32768; rem = l % 32768; K = 256; N = 128; src = upd_w1 + c * 32768; }
        else                   { int l = idx - 393216; int c = l / 49152; rem = l % 49152; K = 128; N = 384; src = upd_w2 + c * 49152; }
        int n = rem / K, k = rem % K;
        val = src[k * N + n];
    } else {
        int l = idx - 540672;             // ro_w1 pad: [n][k], n>=64 -> 0
        int n = l >> 7, k = l & 127;
        val = (n < 64) ? ro_w1[k * 64 + n] : 0.f;
    }
    ushort_t h = f2bf(val);
    dhi[idx] = h;
    dlo[idx] = f2bf(val - bf2f(h));
}

// ---------------- MFMA bf16x3 GEMM, TM x 128 tile (R10 staging; used for UV + readout) ----------------
template<int TM>
__global__ __launch_bounds__(256) void gemm64(
    const float* __restrict__ Af,
    const ushort_t* __restrict__ Bhi, const ushort_t* __restrict__ Blo,
    const float* __restrict__ bias,
    float* __restrict__ C0, float* __restrict__ C1,
    int K, int split, int ld0, int ld1, int act)
{
    constexpr int MI = TM / 16;            // m fragment tiles
    constexpr int EA = TM * 32 / 256;      // A elems per thread per k-iter (8 or 4)
    __shared__ __align__(16) ushort_t Ah[TM * 40];
    __shared__ __align__(16) ushort_t Al[TM * 40];
    __shared__ __align__(16) ushort_t Bh[128 * 40];
    __shared__ __align__(16) ushort_t Bl[128 * 40];
    const int tid = threadIdx.x;
    const int wave = tid >> 6, lane = tid & 63;
    const int row_l = lane & 15, quad = lane >> 4;
    const int wn = wave * 32;
    const int m0 = blockIdx.y * TM, n0 = blockIdx.x * 128;
    const int lrA = tid / (32 / EA);
    const int ksA = (tid % (32 / EA)) * EA;
    const int lrB = tid >> 1, ksB = (tid & 1) * 16;

    f32x4 acc[MI][2];
    #pragma unroll
    for (int i = 0; i < MI; ++i)
        #pragma unroll
        for (int j = 0; j < 2; ++j)
            #pragma unroll
            for (int r = 0; r < 4; ++r) acc[i][j][r] = 0.f;

    for (int k0 = 0; k0 < K; k0 += 32) {
        // ---- stage A (f32 -> hi/lo) ----
        {
            float e[EA];
            const float* ap = &Af[(size_t)(m0 + lrA) * K + k0 + ksA];
            #pragma unroll
            for (int q = 0; q < EA / 4; ++q) {
                float4 v = *(const float4*)(ap + q * 4);
                e[q*4+0] = v.x; e[q*4+1] = v.y; e[q*4+2] = v.z; e[q*4+3] = v.w;
            }
            ushort_t ph[EA], pl[EA];
            #pragma unroll
            for (int t = 0; t < EA; ++t) {
                ushort_t h = f2bf(e[t]);
                ph[t] = h; pl[t] = f2bf(e[t] - bf2f(h));
            }
            if constexpr (EA == 8) {
                *(uint4*)&Ah[lrA * 40 + ksA] = *(uint4*)ph;
                *(uint4*)&Al[lrA * 40 + ksA] = *(uint4*)pl;
            } else {
                *(uint2*)&Ah[lrA * 40 + ksA] = *(uint2*)ph;
                *(uint2*)&Al[lrA * 40 + ksA] = *(uint2*)pl;
            }
        }
        // ---- stage B (16 bf16 per thread per operand) ----
        {
            const ushort_t* bh = &Bhi[(size_t)(n0 + lrB) * K + k0 + ksB];
            const ushort_t* bl = &Blo[(size_t)(n0 + lrB) * K + k0 + ksB];
            *(uint4*)&Bh[lrB * 40 + ksB]     = *(const uint4*)bh;
            *(uint4*)&Bh[lrB * 40 + ksB + 8] = *(const uint4*)(bh + 8);
            *(uint4*)&Bl[lrB * 40 + ksB]     = *(const uint4*)bl;
            *(uint4*)&Bl[lrB * 40 + ksB + 8] = *(const uint4*)(bl + 8);
        }
        __syncthreads();
        bf16x8 ahf[MI], alf[MI], bhf[2], blf[2];
        #pragma unroll
        for (int i = 0; i < MI; ++i) {
            int ar = (i * 16 + row_l) * 40 + quad * 8;
            ahf[i] = *(const bf16x8*)&Ah[ar];
            alf[i] = *(const bf16x8*)&Al[ar];
        }
        #pragma unroll
        for (int j = 0; j < 2; ++j) {
            int br = (wn + j * 16 + row_l) * 40 + quad * 8;
            bhf[j] = *(const bf16x8*)&Bh[br];
            blf[j] = *(const bf16x8*)&Bl[br];
        }
        #pragma unroll
        for (int i = 0; i < MI; ++i)
            #pragma unroll
            for (int j = 0; j < 2; ++j) {
                acc[i][j] = __builtin_amdgcn_mfma_f32_16x16x32_bf16(ahf[i], bhf[j], acc[i][j], 0, 0, 0);
                acc[i][j] = __builtin_amdgcn_mfma_f32_16x16x32_bf16(ahf[i], blf[j], acc[i][j], 0, 0, 0);
                acc[i][j] = __builtin_amdgcn_mfma_f32_16x16x32_bf16(alf[i], bhf[j], acc[i][j], 0, 0, 0);
            }
        __syncthreads();
    }

    #pragma unroll
    for (int j = 0; j < 2; ++j) {
        int col = n0 + wn + j * 16 + row_l;
        float bval = bias ? bias[col] : 0.f;
        float* Cp; int ccol, ld;
        if (col < split) { Cp = C0; ccol = col; ld = ld0; }
        else             { Cp = C1; ccol = col - split; ld = ld1; }
        #pragma unroll
        for (int i = 0; i < MI; ++i)
            #pragma unroll
            for (int r = 0; r < 4; ++r) {
                int row = m0 + i * 16 + quad * 4 + r;
                float v = acc[i][j][r] + bval;
                if (act) v = silu_f(v);
                Cp[(size_t)row * ld + ccol] = v;
            }
    }
}

// ---------------- fused MLP (R10 staging) + optional next-conv phi merge ----------------
// OUT = silu(A@W1+b1)@W2+b2.
// STACK 0: A = s (K1=128). STACK 1: A = [s | norm(vv)] (K1=256, vv layout [n][3][f]).
// FIN 0: write OUT (Nx384 f32) to C.  FIN 1: OUT ('a') to LDS; inline finupd for the
//        block's 32 atoms: s += <uv,vv>*a_sv + a_ss ; v += uv*a_vv.
// NEXT 1 (requires FIN=1): s_new stays in LDS; run next conv's phi MLP
//        (silu(s_new@nW1+nb1)@nW2+nb2) and write to Cnext. Saves a launch + s round-trip.
// 32 rows/block, 256 threads = 4 waves.
template<int STACK, int FIN, int NEXT>
__global__ __launch_bounds__(256) void mlp2_kernel(
    const float* __restrict__ sbuf, const float* __restrict__ vvp,
    const ushort_t* __restrict__ W1h, const ushort_t* __restrict__ W1l,
    const float* __restrict__ b1,
    const ushort_t* __restrict__ W2h, const ushort_t* __restrict__ W2l,
    const float* __restrict__ b2,
    float* __restrict__ C,
    const float* __restrict__ uvb, float* __restrict__ v_io, float* __restrict__ s_io,
    const ushort_t* __restrict__ nW1h, const ushort_t* __restrict__ nW1l,
    const float* __restrict__ nb1,
    const ushort_t* __restrict__ nW2h, const ushort_t* __restrict__ nW2l,
    const float* __restrict__ nb2,
    float* __restrict__ Cnext)
{
    constexpr int K1 = STACK ? 256 : 128;
    constexpr int ASZ = FIN ? 32 * 388 : 4;
    __shared__ __align__(16) ushort_t Ah[32 * 40], Al[32 * 40];
    __shared__ __align__(16) ushort_t Bh[128 * 40], Bl[128 * 40];
    __shared__ __align__(16) ushort_t Hh[32 * 136], Hl[32 * 136];
    __shared__ __align__(16) float Aa[ASZ];
    const int tid = threadIdx.x;
    const int wave = tid >> 6, lane = tid & 63;
    const int row_l = lane & 15, quad = lane >> 4;
    const int wn = wave * 32;
    const int m0 = blockIdx.x * 32;
    const int lrA = tid >> 3;          // 0..31
    const int ksA = (tid & 7) * 4;     // 0,4,..28
    const int lrB = tid >> 1, ksB = (tid & 1) * 16;

    // ---------- stage 1: h = silu(A @ W1 + b1) ----------
    f32x4 acc1[2][2];
    #pragma unroll
    for (int i = 0; i < 2; ++i)
        #pragma unroll
        for (int j = 0; j < 2; ++j)
            #pragma unroll
            for (int r = 0; r < 4; ++r) acc1[i][j][r] = 0.f;

    #pragma unroll 2
    for (int k0 = 0; k0 < K1; k0 += 32) {
        float e[4];
        if (STACK == 0 || k0 + ksA < 128) {
            float4 v = *(const float4*)&sbuf[(size_t)(m0 + lrA) * 128 + k0 + ksA];
            e[0] = v.x; e[1] = v.y; e[2] = v.z; e[3] = v.w;
        } else {
            int f = k0 + ksA - 128;
            const float* px = &vvp[(size_t)(m0 + lrA) * 3 * F + f];
            float4 x = *(const float4*)px;
            float4 y = *(const float4*)(px + F);
            float4 z = *(const float4*)(px + 2 * F);
            e[0] = sqrtf(x.x*x.x + y.x*y.x + z.x*z.x + 1e-15f);
            e[1] = sqrtf(x.y*x.y + y.y*y.y + z.y*z.y + 1e-15f);
            e[2] = sqrtf(x.z*x.z + y.z*y.z + z.z*z.z + 1e-15f);
            e[3] = sqrtf(x.w*x.w + y.w*y.w + z.w*z.w + 1e-15f);
        }
        ushort_t ph[4], pl[4];
        #pragma unroll
        for (int t = 0; t < 4; ++t) {
            ushort_t h = f2bf(e[t]);
            ph[t] = h; pl[t] = f2bf(e[t] - bf2f(h));
        }
        *(uint2*)&Ah[lrA * 40 + ksA] = *(uint2*)ph;
        *(uint2*)&Al[lrA * 40 + ksA] = *(uint2*)pl;
        {
            const ushort_t* bh = &W1h[(size_t)lrB * K1 + k0 + ksB];
            const ushort_t* bl = &W1l[(size_t)lrB * K1 + k0 + ksB];
            *(uint4*)&Bh[lrB * 40 + ksB]     = *(const uint4*)bh;
            *(uint4*)&Bh[lrB * 40 + ksB + 8] = *(const uint4*)(bh + 8);
            *(uint4*)&Bl[lrB * 40 + ksB]     = *(const uint4*)bl;
            *(uint4*)&Bl[lrB * 40 + ksB + 8] = *(const uint4*)(bl + 8);
        }
        __syncthreads();
        bf16x8 ahf[2], alf[2], bhf[2], blf[2];
        #pragma unroll
        for (int i = 0; i < 2; ++i) {
            int ar = (i * 16 + row_l) * 40 + quad * 8;
            ahf[i] = *(const bf16x8*)&Ah[ar];
            alf[i] = *(const bf16x8*)&Al[ar];
        }
        #pragma unroll
        for (int j = 0; j < 2; ++j) {
            int br = (wn + j * 16 + row_l) * 40 + quad * 8;
            bhf[j] = *(const bf16x8*)&Bh[br];
            blf[j] = *(const bf16x8*)&Bl[br];
        }
        #pragma unroll
        for (int i = 0; i < 2; ++i)
            #pragma unroll
            for (int j = 0; j < 2; ++j) {
                acc1[i][j] = __builtin_amdgcn_mfma_f32_16x16x32_bf16(ahf[i], bhf[j], acc1[i][j], 0, 0, 0);
                acc1[i][j] = __builtin_amdgcn_mfma_f32_16x16x32_bf16(ahf[i], blf[j], acc1[i][j], 0, 0, 0);
                acc1[i][j] = __builtin_amdgcn_mfma_f32_16x16x32_bf16(alf[i], bhf[j], acc1[i][j], 0, 0, 0);
            }
        __syncthreads();
    }
    // epilogue 1 -> h in LDS (bf16 hi/lo, [row][k] stride 136)
    #pragma unroll
    for (int j = 0; j < 2; ++j) {
        int col = wn + j * 16 + row_l;
        float bval = b1[col];
        #pragma unroll
        for (int i = 0; i < 2; ++i)
            #pragma unroll
            for (int r = 0; r < 4; ++r) {
                int row = i * 16 + quad * 4 + r;
                float v = silu_f(acc1[i][j][r] + bval);
                ushort_t h = f2bf(v);
                Hh[row * 136 + col] = h;
                Hl[row * 136 + col] = f2bf(v - bf2f(h));
            }
    }
    __syncthreads();

    // ---------- stage 2: OUT = h @ W2 + b2 (3 column tiles of 128) ----------
    for (int ct = 0; ct < 3; ++ct) {
        #pragma unroll
        for (int i = 0; i < 2; ++i)
            #pragma unroll
            for (int j = 0; j < 2; ++j)
                #pragma unroll
                for (int r = 0; r < 4; ++r) acc1[i][j][r] = 0.f;
        for (int k0 = 0; k0 < 128; k0 += 32) {
            {
                const ushort_t* bh = &W2h[(size_t)(ct * 128 + lrB) * 128 + k0 + ksB];
                const ushort_t* bl = &W2l[(size_t)(ct * 128 + lrB) * 128 + k0 + ksB];
                *(uint4*)&Bh[lrB * 40 + ksB]     = *(const uint4*)bh;
                *(uint4*)&Bh[lrB * 40 + ksB + 8] = *(const uint4*)(bh + 8);
                *(uint4*)&Bl[lrB * 40 + ksB]     = *(const uint4*)bl;
                *(uint4*)&Bl[lrB * 40 + ksB + 8] = *(const uint4*)(bl + 8);
            }
            __syncthreads();
            bf16x8 ahf[2], alf[2], bhf[2], blf[2];
            #pragma unroll
            for (int i = 0; i < 2; ++i) {
                int ar = (i * 16 + row_l) * 136 + k0 + quad * 8;
                ahf[i] = *(const bf16x8*)&Hh[ar];
                alf[i] = *(const bf16x8*)&Hl[ar];
            }
            #pragma unroll
            for (int j = 0; j < 2; ++j) {
                int br = (wn + j * 16 + row_l) * 40 + quad * 8;
                bhf[j] = *(const bf16x8*)&Bh[br];
                blf[j] = *(const bf16x8*)&Bl[br];
            }
            #pragma unroll
            for (int i = 0; i < 2; ++i)
                #pragma unroll
                for (int j = 0; j < 2; ++j) {
                    acc1[i][j] = __builtin_amdgcn_mfma_f32_16x16x32_bf16(ahf[i], bhf[j], acc1[i][j], 0, 0, 0);
                    acc1[i][j] = __builtin_amdgcn_mfma_f32_16x16x32_bf16(ahf[i], blf[j], acc1[i][j], 0, 0, 0);
                    acc1[i][j] = __builtin_amdgcn_mfma_f32_16x16x32_bf16(alf[i], bhf[j], acc1[i][j], 0, 0, 0);
                }
            __syncthreads();
        }
        #pragma unroll
        for (int j = 0; j < 2; ++j) {
            int col = ct * 128 + wn + j * 16 + row_l;
            float bval = b2[col];
            #pragma unroll
            for (int i = 0; i < 2; ++i)
                #pragma unroll
                for (int r = 0; r < 4; ++r) {
                    int row = i * 16 + quad * 4 + r;
                    float v = acc1[i][j][r] + bval;
                    if constexpr (FIN) Aa[row * 388 + col] = v;
                    else C[(size_t)(m0 + row) * 384 + col] = v;
                }
        }
    }

    // ---------- inline finupd (FIN=1); s_new also staged to Hh/Hl for NEXT ----------
    if constexpr (FIN) {
        __syncthreads();
        #pragma unroll 4
        for (int p = 0; p < 16; ++p) {
            int idx = p * 256 + tid;           // 0..4095
            int ln = idx >> 7, f = idx & 127;
            int n = m0 + ln;
            size_t vb = (size_t)n * 3 * F + f;
            float ux = uvb[vb], uy = uvb[vb + F], uz = uvb[vb + 2*F];
            float wx = vvp[vb], wy = vvp[vb + F], wz = vvp[vb + 2*F];
            float dot = ux*wx + uy*wy + uz*wz;
            float sn = s_io[(size_t)n * F + f] + dot * Aa[ln * 388 + 128 + f] + Aa[ln * 388 + 256 + f];
            s_io[(size_t)n * F + f] = sn;
            if constexpr (NEXT) {
                ushort_t h = f2bf(sn);
                Hh[ln * 136 + f] = h;          // Hh/Hl free after stage 2
                Hl[ln * 136 + f] = f2bf(sn - bf2f(h));
            }
            float avv = Aa[ln * 388 + f];
            v_io[vb]        += ux * avv;
            v_io[vb + F]    += uy * avv;
            v_io[vb + 2*F]  += uz * avv;
        }
    }

    // ---------- NEXT: next conv's phi MLP from s_new in LDS ----------
    if constexpr (NEXT) {
        __syncthreads();
        // carve next-h storage from Aa (free after finupd)
        ushort_t* H2h = (ushort_t*)Aa;
        ushort_t* H2l = H2h + 32 * 136;
        // stage 1: nh = silu(s_new @ nW1 + nb1), K=128
        #pragma unroll
        for (int i = 0; i < 2; ++i)
            #pragma unroll
            for (int j = 0; j < 2; ++j)
                #pragma unroll
                for (int r = 0; r < 4; ++r) acc1[i][j][r] = 0.f;
        for (int k0 = 0; k0 < 128; k0 += 32) {
            {
                const ushort_t* bh = &nW1h[(size_t)lrB * 128 + k0 + ksB];
                const ushort_t* bl = &nW1l[(size_t)lrB * 128 + k0 + ksB];
                *(uint4*)&Bh[lrB * 40 + ksB]     = *(const uint4*)bh;
                *(uint4*)&Bh[lrB * 40 + ksB + 8] = *(const uint4*)(bh + 8);
                *(uint4*)&Bl[lrB * 40 + ksB]     = *(const uint4*)bl;
                *(uint4*)&Bl[lrB * 40 + ksB + 8] = *(const uint4*)(bl + 8);
            }
            __syncthreads();
            bf16x8 ahf[2], alf[2], bhf[2], blf[2];
            #pragma unroll
            for (int i = 0; i < 2; ++i) {
                int ar = (i * 16 + row_l) * 136 + k0 + quad * 8;
                ahf[i] = *(const bf16x8*)&Hh[ar];
                alf[i] = *(const bf16x8*)&Hl[ar];
            }
            #pragma unroll
            for (int j = 0; j < 2; ++j) {
                int br = (wn + j * 16 + row_l) * 40 + quad * 8;
                bhf[j] = *(const bf16x8*)&Bh[br];
                blf[j] = *(const bf16x8*)&Bl[br];
            }
            #pragma unroll
            for (int i = 0; i < 2; ++i)
                #pragma unroll
                for (int j = 0; j < 2; ++j) {
                    acc1[i][j] = __builtin_amdgcn_mfma_f32_16x16x32_bf16(ahf[i], bhf[j], acc1[i][j], 0, 0, 0);
                    acc1[i][j] = __builtin_amdgcn_mfma_f32_16x16x32_bf16(ahf[i], blf[j], acc1[i][j], 0, 0, 0);
                    acc1[i][j] = __builtin_amdgcn_mfma_f32_16x16x32_bf16(alf[i], bhf[j], acc1[i][j], 0, 0, 0);
                }
            __syncthreads();
        }
        #pragma unroll
        for (int j = 0; j < 2; ++j) {
            int col = wn + j * 16 + row_l;
            float bval = nb1[col];
            #pragma unroll
            for (int i = 0; i < 2; ++i)
                #pragma unroll
                for (int r = 0; r < 4; ++r) {
                    int row = i * 16 + quad * 4 + r;
                    float v = silu_f(acc1[i][j][r] + bval);
                    ushort_t h = f2bf(v);
                    H2h[row * 136 + col] = h;
                    H2l[row * 136 + col] = f2bf(v - bf2f(h));
                }
        }
        __syncthreads();
        // stage 2: phi = nh @ nW2 + nb2 -> Cnext (3 column tiles)
        for (int ct = 0; ct < 3; ++ct) {
            #pragma unroll
            for (int i = 0; i < 2; ++i)
                #pragma unroll
                for (int j = 0; j < 2; ++j)
                    #pragma unroll
                    for (int r = 0; r < 4; ++r) acc1[i][j][r] = 0.f;
            for (int k0 = 0; k0 < 128; k0 += 32) {
                {
                    const ushort_t* bh = &nW2h[(size_t)(ct * 128 + lrB) * 128 + k0 + ksB];
                    const ushort_t* bl = &nW2l[(size_t)(ct * 128 + lrB) * 128 + k0 + ksB];
                    *(uint4*)&Bh[lrB * 40 + ksB]     = *(const uint4*)bh;
                    *(uint4*)&Bh[lrB * 40 + ksB + 8] = *(const uint4*)(bh + 8);
                    *(uint4*)&Bl[lrB * 40 + ksB]     = *(const uint4*)bl;
                    *(uint4*)&Bl[lrB * 40 + ksB + 8] = *(const uint4*)(bl + 8);
                }
                __syncthreads();
                bf16x8 ahf[2], alf[2], bhf[2], blf[2];
                #pragma unroll
                for (int i = 0; i < 2; ++i) {
                    int ar = (i * 16 + row_l) * 136 + k0 + quad * 8;
                    ahf[i] = *(const bf16x8*)&H2h[ar];
                    alf[i] = *(const bf16x8*)&H2l[ar];
                }
                #pragma unroll
                for (int j = 0; j < 2; ++j) {
                    int br = (wn + j * 16 + row_l) * 40 + quad * 8;
                    bhf[j] = *(const bf16x8*)&Bh[br];
                    blf[j] = *(const bf16x8*)&Bl[br];
                }
                #pragma unroll
                for (int i = 0; i < 2; ++i)
                    #pragma unroll
                    for (int j = 0; j < 2; ++j) {
                        acc1[i][j] = __builtin_amdgcn_mfma_f32_16x16x32_bf16(ahf[i], bhf[j], acc1[i][j], 0, 0, 0);
                        acc1[i][j] = __builtin_amdgcn_mfma_f32_16x16x32_bf16(ahf[i], blf[j], acc1[i][j], 0, 0, 0);
                        acc1[i][j] = __builtin_amdgcn_mfma_f32_16x16x32_bf16(alf[i], bhf[j], acc1[i][j], 0, 0, 0);
                    }
                __syncthreads();
            }
            #pragma unroll
            for (int j = 0; j < 2; ++j) {
                int col = ct * 128 + wn + j * 16 + row_l;
                float bval = nb2[col];
                #pragma unroll
                for (int i = 0; i < 2; ++i)
                    #pragma unroll
                    for (int r = 0; r < 4; ++r) {
                        int row = i * 16 + quad * 4 + r;
                        Cnext[(size_t)(m0 + row) * 384 + col] = acc1[i][j][r] + bval;
                    }
            }
        }
    }
}

// ---------------- atom-centric message gather (atomic-free, packed records) ----------------
// v layout: [n][3][f]. ZVIN=1: v_in is implicitly zero (conv 0) — skip reads.
template<int ZVIN>
__global__ __launch_bounds__(128) void msg_gather(
    const float* __restrict__ phi, const float* __restrict__ rec,
    const float* __restrict__ rbf_w, const float* __restrict__ rbf_b,
    const float* __restrict__ v_in, float* __restrict__ s,
    float* __restrict__ v_out, const int* __restrict__ offsets,
    const int* __restrict__ cnt)
{
    const int n = blockIdx.x, tid = threadIdx.x;
    float W0[N_RBF], W1[N_RBF], W2[N_RBF];
    #pragma unroll
    for (int k = 0; k < N_RBF; ++k) {
        W0[k] = rbf_w[k*3*F + tid];
        W1[k] = rbf_w[k*3*F + F + tid];
        W2[k] = rbf_w[k*3*F + 2*F + tid];
    }
    const float b0 = rbf_b[tid], b1 = rbf_b[F + tid], b2 = rbf_b[2*F + tid];
    float ds = 0.f, dvx = 0.f, dvy = 0.f, dvz = 0.f;
    const int off = offsets[n], c = cnt[n];
    const float* r = rec + (size_t)off * REC;
    #pragma unroll 2
    for (int t = 0; t < c; ++t, r += REC) {
        int j = __float_as_int(r[0]);
        float ev = r[1];
        float ux = r[2], uy = r[3], uz = r[4];
        float w0 = b0 * ev, w1 = b1 * ev, w2 = b2 * ev;
        #pragma unroll
        for (int k = 0; k < N_RBF; ++k) {
            float rk = r[5 + k];
            w0 += rk * W0[k]; w1 += rk * W1[k]; w2 += rk * W2[k];
        }
        const float* prow = phi + (size_t)j * 3 * F;
        float s0 = prow[tid] * w0;
        float s1 = prow[F + tid] * w1;
        float s2 = prow[2*F + tid] * w2;
        ds  += s1;
        if constexpr (ZVIN) {
            dvx += s2*ux; dvy += s2*uy; dvz += s2*uz;
        } else {
            const float* vrow = v_in + (size_t)j * 3 * F;
            dvx += s2*ux + s0 * vrow[tid];
            dvy += s2*uy + s0 * vrow[F + tid];
            dvz += s2*uz + s0 * vrow[2*F + tid];
        }
    }
    s[(size_t)n * F + tid] += ds;
    size_t vb = (size_t)n * 3 * F + tid;
    if constexpr (ZVIN) {
        v_out[vb]       = dvx;
        v_out[vb + F]   = dvy;
        v_out[vb + 2*F] = dvz;
    } else {
        v_out[vb]       = v_in[vb]       + dvx;
        v_out[vb + F]   = v_in[vb + F]   + dvy;
        v_out[vb + 2*F] = v_in[vb + 2*F] + dvz;
    }
}

// ---------------- readout reduce: atom_e = h2[n][0:64]·w2 + b2; LDS mol table ----------------
__global__ __launch_bounds__(256) void rreduce_kernel(
    const float* __restrict__ h2, const float* __restrict__ w2,
    const float* __restrict__ b2, const int* __restrict__ mol,
    float* __restrict__ out)
{
    __shared__ float molacc[128];
    int tid = threadIdx.x, wave = tid >> 6, lane = tid & 63;
    if (tid < 128) molacc[tid] = 0.f;
    float w2v = w2[lane], b2v = b2[0];
    int n0 = blockIdx.x * 250;
    __syncthreads();
    for (int t = wave; t < 250; t += 4) {
        int n = n0 + t;
        float val = h2[(size_t)n * 128 + lane] * w2v;
        #pragma unroll
        for (int o = 32; o > 0; o >>= 1) val += __shfl_down(val, o);
        if (lane == 0) atomicAdd(&molacc[mol[n]], val + b2v);
    }
    __syncthreads();
    int lo = mol[n0], hi = mol[n0 + 249];
    for (int m = lo + tid; m <= hi; m += 256)
        atomicAdd(&out[m], molacc[m]);
}

extern "C" void kernel_launch(void* const* d_in, const int* in_sizes, int n_in,
                              void* d_out, int out_size, void* d_ws, size_t ws_size,
                              hipStream_t stream)
{
    const float* xyz    = (const float*)d_in[0];
    const float* emb    = (const float*)d_in[1];
    const float* msg_w1 = (const float*)d_in[2];
    const float* msg_b1 = (const float*)d_in[3];
    const float* msg_w2 = (const float*)d_in[4];
    const float* msg_b2 = (const float*)d_in[5];
    const float* rbf_w  = (const float*)d_in[6];
    const float* rbf_b  = (const float*)d_in[7];
    const float* upd_u  = (const float*)d_in[8];
    const float* upd_v  = (const float*)d_in[9];
    const float* upd_w1 = (const float*)d_in[10];
    const float* upd_b1 = (const float*)d_in[11];
    const float* upd_w2 = (const float*)d_in[12];
    const float* upd_b2 = (const float*)d_in[13];
    const float* ro_w1  = (const float*)d_in[14];
    const float* ro_b1  = (const float*)d_in[15];
    const float* ro_w2  = (const float*)d_in[16];
    const float* ro_b2  = (const float*)d_in[17];
    const int*   z      = (const int*)d_in[18];
    const int*   nbrs   = (const int*)d_in[19];
    const int*   molidx = (const int*)d_in[20];
    float* out = (float*)d_out;

    float* ws = (float*)d_ws;
    size_t off = 0;
    auto alloc = [&](size_t n) { float* p = ws + off; off += n; return p; };
    float* s_buf   = alloc(NFC);
    float* v1_buf  = alloc(3 * NFC);       // [n][3][f]
    float* v2_buf  = alloc(3 * NFC);
    float* uv_buf  = alloc(3 * NFC);
    float* vv_buf  = alloc(3 * NFC);
    float* phi_buf = alloc(3 * NFC);       // phi / readout-hidden
    float* rbfe    = alloc((size_t)N_EDGES * N_RBF);
    float* envb    = alloc(N_EDGES);
    float* unitb   = alloc((size_t)N_EDGES * 3);
    float* edgerec = alloc((size_t)N_EDGES * REC);
    ushort_t* wbf_hi = (ushort_t*)alloc(WPREP_W / 2 + 64);
    ushort_t* wbf_lo = (ushort_t*)alloc(WPREP_W / 2 + 64);
    float* robias   = alloc(128);
    int* cnt        = (int*)alloc(N_ATOMS);
    int* cursor     = (int*)alloc(N_ATOMS);
    int* offsets    = (int*)alloc(N_ATOMS);

    // bf16 weight sub-offsets (elements, see wprep_kernel)
    const size_t oW1 = 0, oW2 = 49152, oUV = 196608, oU1 = 294912, oU2 = 393216, oRO = 540672;

    hipMemsetAsync(out, 0, sizeof(float) * N_MOLS, stream);
    hipMemsetAsync(cnt, 0, sizeof(int) * 2 * N_ATOMS, stream);   // cnt + cursor adjacent

    geom_kernel<<<dim3((N_EDGES + 255) / 256), dim3(256), 0, stream>>>(
        xyz, nbrs, rbfe, envb, unitb, cnt);
    scan_kernel<<<dim3(1), dim3(1024), 0, stream>>>(cnt, offsets);
    scatter_kernel<<<dim3((N_EDGES + 255) / 256), dim3(256), 0, stream>>>(
        nbrs, envb, rbfe, unitb, offsets, cursor, edgerec);
    embed_kernel<<<dim3(N_ATOMS * F / 256), dim3(256), 0, stream>>>(emb, z, s_buf);
    wprep_kernel<<<dim3((WPREP_TOTAL + 255) / 256), dim3(256), 0, stream>>>(
        msg_w1, msg_w2, upd_u, upd_v, upd_w1, upd_w2, ro_w1, ro_b1,
        wbf_hi, wbf_lo, robias);

    // conv 0 phi (separate kernel)
    mlp2_kernel<0, 0, 0><<<dim3(NP/32), dim3(256), 0, stream>>>(
        s_buf, nullptr,
        wbf_hi + oW1, wbf_lo + oW1, msg_b1,
        wbf_hi + oW2, wbf_lo + oW2, msg_b2,
        phi_buf, nullptr, nullptr, nullptr,
        nullptr, nullptr, nullptr, nullptr, nullptr, nullptr, nullptr);

    float* vin = v1_buf;
    float* vout = v2_buf;
    for (int i = 0; i < 3; ++i) {
        // atomic-free message gather: s += ds in place; vout = vin + dv
        if (i == 0)
            msg_gather<1><<<dim3(N_ATOMS), dim3(128), 0, stream>>>(
                phi_buf, edgerec, rbf_w + (size_t)i*N_RBF*3*F, rbf_b + (size_t)i*3*F,
                vin, s_buf, vout, offsets, cnt);
        else
            msg_gather<0><<<dim3(N_ATOMS), dim3(128), 0, stream>>>(
                phi_buf, edgerec, rbf_w + (size_t)i*N_RBF*3*F, rbf_b + (size_t)i*3*F,
                vin, s_buf, vout, offsets, cnt);
        // fused u_v|v_v: one GEMM over M=3*NP rows ([n][3] row order), split-column (756 blocks)
        gemm64<64><<<dim3(2, 3*NP/64), dim3(256), 0, stream>>>(
            vout,
            wbf_hi + oUV + (size_t)i*32768, wbf_lo + oUV + (size_t)i*32768,
            nullptr, uv_buf, vv_buf,
            128, F, F, F, 0);
        // upd MLP + finupd, merged with next conv's phi MLP (i<2)
        if (i < 2)
            mlp2_kernel<1, 1, 1><<<dim3(NP/32), dim3(256), 0, stream>>>(
                s_buf, vv_buf,
                wbf_hi + oU1 + (size_t)i*32768, wbf_lo + oU1 + (size_t)i*32768,
                upd_b1 + (size_t)i*F,
                wbf_hi + oU2 + (size_t)i*49152, wbf_lo + oU2 + (size_t)i*49152,
                upd_b2 + (size_t)i*3*F,
                nullptr, uv_buf, vout, s_buf,
                wbf_hi + oW1 + (size_t)(i+1)*16384, wbf_lo + oW1 + (size_t)(i+1)*16384,
                msg_b1 + (size_t)(i+1)*F,
                wbf_hi + oW2 + (size_t)(i+1)*49152, wbf_lo + oW2 + (size_t)(i+1)*49152,
                msg_b2 + (size_t)(i+1)*3*F,
                phi_buf);
        else
            mlp2_kernel<1, 1, 0><<<dim3(NP/32), dim3(256), 0, stream>>>(
                s_buf, vv_buf,
                wbf_hi + oU1 + (size_t)i*32768, wbf_lo + oU1 + (size_t)i*32768,
                upd_b1 + (size_t)i*F,
                wbf_hi + oU2 + (size_t)i*49152, wbf_lo + oU2 + (size_t)i*49152,
                upd_b2 + (size_t)i*3*F,
                nullptr, uv_buf, vout, s_buf,
                nullptr, nullptr, nullptr, nullptr, nullptr, nullptr, nullptr);
        float* tmp = vin; vin = vout; vout = tmp;
    }

    // readout: h2 = silu(s @ ro_w1pad + b1pad) via MFMA (252 blocks), then LDS-table reduce
    gemm64<32><<<dim3(1, NP/32), dim3(256), 0, stream>>>(
        s_buf,
        wbf_hi + oRO, wbf_lo + oRO,
        robias, phi_buf, phi_buf,
        128, 128, 128, 128, 1);
    rreduce_kernel<<<dim3(32), dim3(256), 0, stream>>>(
        phi_buf, ro_w2, ro_b2, molidx, out);
}